// Round 2
// baseline (1100.283 us; speedup 1.0000x reference)
//
#include <hip/hip_runtime.h>
#include <stdint.h>

typedef unsigned short u16;
using bf16x8 = __attribute__((ext_vector_type(8))) __bf16;
using f32x4  = __attribute__((ext_vector_type(4))) float;

// ---------- helpers ----------
__device__ __forceinline__ u16 f2bf(float f) {
    uint32_t u = __float_as_uint(f);
    u += 0x7fffu + ((u >> 16) & 1u);          // round-to-nearest-even
    return (u16)(u >> 16);
}
__device__ __forceinline__ float bf2f(u16 u) {
    return __uint_as_float(((uint32_t)u) << 16);
}
__device__ __forceinline__ void gload16(const void* g, void* l) {
    // async global->LDS, 16B per lane; LDS dest = wave-uniform base + lane*16
    __builtin_amdgcn_global_load_lds(
        (__attribute__((address_space(1))) void*)(uintptr_t)g,
        (__attribute__((address_space(3))) void*)(uintptr_t)l,
        16, 0, 0);
}

// ---------- LayerNorm: fp32 in -> bf16 (mode 0) or fp32 (mode 1) out ----------
template <int OUTF32>
__global__ __launch_bounds__(256) void ln_kernel(const float* __restrict__ in,
                                                 const float* __restrict__ g,
                                                 const float* __restrict__ b,
                                                 void* __restrict__ out, int D) {
    const int row = blockIdx.x;
    const int tid = threadIdx.x;
    const float* x = in + (size_t)row * D;
    const int nv = D >> 8;                    // 4 for D=1024, 1 for D=256
    float v[4];
    float s1 = 0.f, s2 = 0.f;
    for (int i = 0; i < nv; ++i) {
        float t = x[tid + (i << 8)];
        v[i] = t; s1 += t; s2 += t * t;
    }
    for (int o = 1; o < 64; o <<= 1) {
        s1 += __shfl_xor(s1, o, 64);
        s2 += __shfl_xor(s2, o, 64);
    }
    __shared__ float r1[4], r2[4];
    const int w = tid >> 6;
    if ((tid & 63) == 0) { r1[w] = s1; r2[w] = s2; }
    __syncthreads();
    s1 = r1[0] + r1[1] + r1[2] + r1[3];
    s2 = r2[0] + r2[1] + r2[2] + r2[3];
    const float mean = s1 / (float)D;
    const float var  = s2 / (float)D - mean * mean;
    const float inv  = rsqrtf(var + 1e-5f);
    for (int i = 0; i < nv; ++i) {
        int c = tid + (i << 8);
        float y = (v[i] - mean) * inv * g[c] + b[c];
        if (OUTF32) ((float*)out)[(size_t)row * D + c] = y;
        else        ((u16*)out)[(size_t)row * D + c] = f2bf(y);
    }
}

// ---------- weight transpose + fp32->bf16 convert: W[K][ldw](first N cols) -> Wt[N][K] ----------
__global__ __launch_bounds__(256) void wconvert_t(const float* __restrict__ W,
                                                  u16* __restrict__ Wt,
                                                  int K, int N, int ldw) {
    __shared__ float tile[32][33];
    const int k0 = blockIdx.x * 32, n0 = blockIdx.y * 32;
    const int tx = threadIdx.x & 31, ty = threadIdx.x >> 5;  // 32 x 8
    for (int i = 0; i < 4; ++i)
        tile[ty + i * 8][tx] = W[(size_t)(k0 + ty + i * 8) * ldw + n0 + tx];
    __syncthreads();
    for (int i = 0; i < 4; ++i)
        Wt[(size_t)(n0 + ty + i * 8) * K + k0 + tx] = f2bf(tile[tx][ty + i * 8]);
}

// ---------- GEMM: C[M,N] = A[M,K](bf16) * Bt[N,K](bf16)^T, 128x128 tile, BK=32 ----------
// EPI: 0 = bf16 out (+bias) ; 1 = silu -> bf16 (+bias) ; 2 = f32 out (+bias) ;
//      3 = f32 out = res + rscale*(acc+bias)
template <int EPI>
__global__ __launch_bounds__(256) void gemm_bf16(const u16* __restrict__ A,
                                                 const u16* __restrict__ Bt,
                                                 const float* __restrict__ bias,
                                                 const float* __restrict__ res,
                                                 float rscale,
                                                 void* __restrict__ outp,
                                                 int M, int N, int K) {
    __shared__ u16 sA[128 * 32];
    __shared__ u16 sB[128 * 32];
    const int tid = threadIdx.x;
    const int lane = tid & 63;
    const int w = tid >> 6;
    const int wm = w >> 1, wn = w & 1;        // 2x2 wave grid
    const int fr = lane & 15, fq = lane >> 4;
    const int bm0 = blockIdx.y * 128, bn0 = blockIdx.x * 128;

    f32x4 acc[4][4] = {};

    const u16* ga0 = A  + (size_t)(bm0 + (tid >> 2)) * K + ((tid & 3) << 3);
    const u16* gb0 = Bt + (size_t)(bn0 + (tid >> 2)) * K + ((tid & 3) << 3);
    const size_t rstep = (size_t)64 * K;
    u16* la0 = sA + ((tid >> 6) << 9);        // wave-uniform base (w*512 elems)
    u16* lb0 = sB + ((tid >> 6) << 9);

    for (int kt = 0; kt < K; kt += 32) {
        __syncthreads();
        gload16(ga0 + kt,         la0);
        gload16(ga0 + rstep + kt, la0 + 2048);
        gload16(gb0 + kt,         lb0);
        gload16(gb0 + rstep + kt, lb0 + 2048);
        __syncthreads();
        bf16x8 afr[4], bfr[4];
        const u16* pa = sA + (wm * 64 + fr) * 32 + fq * 8;
        const u16* pb = sB + (wn * 64 + fr) * 32 + fq * 8;
#pragma unroll
        for (int i = 0; i < 4; ++i) {
            afr[i] = *(const bf16x8*)(pa + i * 512);
            bfr[i] = *(const bf16x8*)(pb + i * 512);
        }
#pragma unroll
        for (int mi = 0; mi < 4; ++mi)
#pragma unroll
            for (int ni = 0; ni < 4; ++ni)
                acc[mi][ni] = __builtin_amdgcn_mfma_f32_16x16x32_bf16(
                    afr[mi], bfr[ni], acc[mi][ni], 0, 0, 0);
    }

    // epilogue: D row=(lane>>4)*4+reg, col=lane&15 within each 16x16 frag
#pragma unroll
    for (int mi = 0; mi < 4; ++mi) {
#pragma unroll
        for (int ni = 0; ni < 4; ++ni) {
            const int r0 = bm0 + wm * 64 + mi * 16 + fq * 4;
            const int c  = bn0 + wn * 64 + ni * 16 + fr;
            const float bv = bias ? bias[c] : 0.f;
#pragma unroll
            for (int r = 0; r < 4; ++r) {
                float v = acc[mi][ni][r] + bv;
                const size_t idx = (size_t)(r0 + r) * N + c;
                if (EPI == 0) {
                    ((u16*)outp)[idx] = f2bf(v);
                } else if (EPI == 1) {
                    v = v / (1.f + __expf(-v));           // silu
                    ((u16*)outp)[idx] = f2bf(v);
                } else if (EPI == 2) {
                    ((float*)outp)[idx] = v;
                } else {
                    ((float*)outp)[idx] = res[idx] + rscale * v;
                }
            }
        }
    }
}

// ---------- RoPE tables: ctab/stab [T=1024][32] ----------
__global__ __launch_bounds__(256) void rope_tables_kernel(float* __restrict__ ct,
                                                          float* __restrict__ st) {
    const int i = blockIdx.x * 256 + threadIdx.x;   // 32768
    const int t = i >> 5, j = i & 31;
    const float inv = powf(10000.f, -(float)j / 32.f);
    const float f = (float)t * inv;
    ct[i] = cosf(f);
    st[i] = sinf(f);
}

// ---------- RoPE apply in place on bf16, optional output scale ----------
__global__ __launch_bounds__(256) void rope_kernel(u16* __restrict__ buf,
                                                   const float* __restrict__ ct,
                                                   const float* __restrict__ st,
                                                   int hmask, int hshift, int rstride,
                                                   float scale) {
    const int i = blockIdx.x * 256 + threadIdx.x;
    const int j = i & 31;
    const int hh = (i >> 5) & hmask;
    const int m = i >> (5 + hshift);
    const int t = m & 1023;
    u16* p = buf + (size_t)m * rstride + hh * 64 + j;
    const float c = ct[t * 32 + j], s = st[t * 32 + j];
    const float x1 = bf2f(p[0]), x2 = bf2f(p[32]);
    p[0]  = f2bf((x1 * c - x2 * s) * scale);
    p[32] = f2bf((x2 * c + x1 * s) * scale);
}

// ---------- V transpose: KV[(b*1024+t)*512 + 256 + kh*64 + hd] -> Vt[(b*4+kh)*64+hd][t] ----------
__global__ __launch_bounds__(256) void vtranspose_kernel(const u16* __restrict__ KV,
                                                         u16* __restrict__ Vt) {
    __shared__ u16 tile[32][33];
    const int t0 = blockIdx.x * 32, h0 = blockIdx.y * 32;
    const int bk = blockIdx.z;                 // b*4 + kh
    const int b = bk >> 2, kh = bk & 3;
    const int tx = threadIdx.x & 31, ty = threadIdx.x >> 5;
    for (int i = 0; i < 4; ++i)
        tile[ty + i * 8][tx] =
            KV[(size_t)(b * 1024 + t0 + ty + i * 8) * 512 + 256 + kh * 64 + h0 + tx];
    __syncthreads();
    for (int i = 0; i < 4; ++i)
        Vt[((size_t)bk * 64 + h0 + ty + i * 8) * 1024 + t0 + tx] = tile[tx][ty + i * 8];
}

// ---------- fused SDPA v2: swapped QK^T, in-lane softmax, barrier-free ----------
// grid (b*h=128, qtile=16); 4 waves/block, each wave owns 16 q-rows.
// S^T = mfma(K,Q): lane(fq,fr) holds S[kv = kv0+nb*16+fq*4+r][q = q0+fr].
// Row max/sum are in-lane (15 ops) + 2 shfl_xor(16,32). P staged in a
// wave-private padded LDS slab (stride 72 elems -> conflict-free b128 reads).
// O^T = mfma(V^T, P). T13 defer-max with THR=8. No __syncthreads anywhere.
__global__ __launch_bounds__(256) void attn_kernel(const u16* __restrict__ Q,
                                                   const u16* __restrict__ KV,
                                                   const u16* __restrict__ Vt,
                                                   u16* __restrict__ O) {
    __shared__ __align__(16) u16 sP[4 * 16 * 72];
    const int tid = threadIdx.x, lane = tid & 63, w = tid >> 6;
    const int fr = lane & 15, fq = lane >> 4;
    const int bh = blockIdx.x, b = bh >> 4, h = bh & 15, kh = h >> 2;
    const int q0 = blockIdx.y * 64 + w * 16;
    const int qrow = b * 1024 + q0 + fr;

    bf16x8 qf[2];
    qf[0] = *(const bf16x8*)(Q + (size_t)qrow * 1024 + h * 64 + fq * 8);
    qf[1] = *(const bf16x8*)(Q + (size_t)qrow * 1024 + h * 64 + 32 + fq * 8);

    f32x4 oacc[4] = {};
    float mrun = -1e30f, lrun = 0.f;
    u16* sPw = sP + w * (16 * 72);
    const u16* Kbase = KV + (size_t)b * 1024 * 512 + kh * 64;
    const u16* Vbase = Vt + (size_t)(b * 4 + kh) * 64 * 1024;

    for (int kv0 = 0; kv0 < 1024; kv0 += 64) {
        // ---- S^T = K x Q^T (Q pre-scaled by 1/8 in rope) ----
        f32x4 sacc[4] = {};
#pragma unroll
        for (int ks = 0; ks < 2; ++ks)
#pragma unroll
            for (int nb = 0; nb < 4; ++nb) {
                const bf16x8 kf = *(const bf16x8*)(
                    Kbase + (size_t)(kv0 + nb * 16 + fr) * 512 + ks * 32 + fq * 8);
                sacc[nb] = __builtin_amdgcn_mfma_f32_16x16x32_bf16(kf, qf[ks], sacc[nb], 0, 0, 0);
            }
        // ---- in-lane max over 16 kv, then reduce across the 4 fq lanes ----
        float pm;
        {
            float a0 = fmaxf(fmaxf(sacc[0][0], sacc[0][1]), fmaxf(sacc[0][2], sacc[0][3]));
            float a1 = fmaxf(fmaxf(sacc[1][0], sacc[1][1]), fmaxf(sacc[1][2], sacc[1][3]));
            float a2 = fmaxf(fmaxf(sacc[2][0], sacc[2][1]), fmaxf(sacc[2][2], sacc[2][3]));
            float a3 = fmaxf(fmaxf(sacc[3][0], sacc[3][1]), fmaxf(sacc[3][2], sacc[3][3]));
            pm = fmaxf(fmaxf(a0, a1), fmaxf(a2, a3));
        }
        pm = fmaxf(pm, __shfl_xor(pm, 16, 64));
        pm = fmaxf(pm, __shfl_xor(pm, 32, 64));
        // ---- T13: rescale only when max grew past threshold ----
        if (!__all(pm <= mrun + 8.f)) {
            const float mn = fmaxf(mrun, pm);
            const float al = __expf(mrun - mn);
            mrun = mn;
            lrun *= al;
#pragma unroll
            for (int f = 0; f < 4; ++f) {
                f32x4 t = oacc[f];
#pragma unroll
                for (int r = 0; r < 4; ++r) t[r] *= al;
                oacc[f] = t;
            }
        }
        // ---- P = exp(S - m), in-lane rowsum, pack to LDS ----
        float p[4][4];
        float rs = 0.f;
#pragma unroll
        for (int nb = 0; nb < 4; ++nb) {
#pragma unroll
            for (int r = 0; r < 4; ++r) {
                p[nb][r] = __expf(sacc[nb][r] - mrun);
                rs += p[nb][r];
            }
        }
        rs += __shfl_xor(rs, 16, 64);
        rs += __shfl_xor(rs, 32, 64);
        lrun += rs;
#pragma unroll
        for (int nb = 0; nb < 4; ++nb) {
            union { uint2 u2; u16 hh[4]; } pk;
#pragma unroll
            for (int r = 0; r < 4; ++r) pk.hh[r] = f2bf(p[nb][r]);
            *(uint2*)(sPw + fr * 72 + nb * 16 + fq * 4) = pk.u2;
        }
        // wave-local write->read ordering: drain LDS queue, pin the scheduler
        asm volatile("s_waitcnt lgkmcnt(0)" ::: "memory");
        __builtin_amdgcn_sched_barrier(0);
        // ---- O^T += V^T x P^T ----
#pragma unroll
        for (int ks2 = 0; ks2 < 2; ++ks2) {
            const bf16x8 pf = *(const bf16x8*)(sPw + fr * 72 + ks2 * 32 + fq * 8);
#pragma unroll
            for (int f = 0; f < 4; ++f) {
                const bf16x8 vf = *(const bf16x8*)(
                    Vbase + (size_t)(f * 16 + fr) * 1024 + kv0 + ks2 * 32 + fq * 8);
                oacc[f] = __builtin_amdgcn_mfma_f32_16x16x32_bf16(vf, pf, oacc[f], 0, 0, 0);
            }
        }
        // keep next tile's P-writes after this tile's P-reads (compiler order)
        asm volatile("" ::: "memory");
    }

    const float linv = 1.f / lrun;
#pragma unroll
    for (int f = 0; f < 4; ++f) {
        union { uint2 u2; u16 hh[4]; } ok;
#pragma unroll
        for (int r = 0; r < 4; ++r) ok.hh[r] = f2bf(oacc[f][r] * linv);
        *(uint2*)(O + (size_t)qrow * 1024 + h * 64 + f * 16 + fq * 4) = ok.u2;
    }
}

// ---------- GLU: in [M,2048] bf16 -> out [M,1024] bf16 ----------
__global__ __launch_bounds__(256) void glu_kernel(const u16* __restrict__ in,
                                                  u16* __restrict__ out) {
    const size_t i = (size_t)blockIdx.x * 256 + threadIdx.x;  // 8192*1024 total
    const size_t m = i >> 10;
    const int j = (int)(i & 1023);
    const float a = bf2f(in[m * 2048 + j]);
    const float g = bf2f(in[m * 2048 + 1024 + j]);
    out[i] = f2bf(a / (1.f + __expf(-g)));
}

// ---------- depthwise conv(K=31) + BN + SiLU: [B,T,D] bf16 -> bf16 ----------
__global__ __launch_bounds__(256) void dwconv_kernel(const u16* __restrict__ G,
                                                     const float* __restrict__ wt,
                                                     const float* __restrict__ wb,
                                                     const float* __restrict__ bg,
                                                     const float* __restrict__ bb,
                                                     const float* __restrict__ rm,
                                                     const float* __restrict__ rv,
                                                     u16* __restrict__ out) {
    __shared__ u16 sg[38 * 256];
    const int tid = threadIdx.x;
    const int d = blockIdx.x * 256 + tid;
    const int t0 = blockIdx.y * 8;
    const int b = blockIdx.z;
    const size_t base = (size_t)b * 1024 * 1024 + d;
    for (int i = 0; i < 38; ++i) {
        const int t = t0 - 15 + i;
        sg[i * 256 + tid] = (t >= 0 && t < 1024) ? G[base + (size_t)t * 1024] : (u16)0;
    }
    __syncthreads();
    float wreg[31];
#pragma unroll
    for (int k = 0; k < 31; ++k) wreg[k] = wt[d * 31 + k];
    const float scale = bg[d] * rsqrtf(rv[d] + 1e-5f);
    const float addv = wb[d] - rm[d];
#pragma unroll
    for (int j = 0; j < 8; ++j) {
        float acc = 0.f;
#pragma unroll
        for (int k = 0; k < 31; ++k) acc += bf2f(sg[(j + k) * 256 + tid]) * wreg[k];
        float y = (acc + addv) * scale + bb[d];
        y = y / (1.f + __expf(-y));               // silu
        out[base + (size_t)(t0 + j) * 1024] = f2bf(y);
    }
}

// =====================================================================
extern "C" void kernel_launch(void* const* d_in, const int* in_sizes, int n_in,
                              void* d_out, int out_size, void* d_ws, size_t ws_size,
                              hipStream_t stream) {
    (void)in_sizes; (void)n_in; (void)out_size;

    const float* x       = (const float*)d_in[0];
    const float* ff1_ng  = (const float*)d_in[1];
    const float* ff1_nb  = (const float*)d_in[2];
    const float* ff1_w1  = (const float*)d_in[3];
    const float* ff1_b1  = (const float*)d_in[4];
    const float* ff1_w2  = (const float*)d_in[5];
    const float* ff1_b2  = (const float*)d_in[6];
    const float* attn_ng = (const float*)d_in[7];
    const float* attn_nb = (const float*)d_in[8];
    const float* wq      = (const float*)d_in[9];
    const float* wkva    = (const float*)d_in[10];
    const float* kvn_g   = (const float*)d_in[11];
    const float* kvn_b   = (const float*)d_in[12];
    const float* wkvb    = (const float*)d_in[13];
    const float* wo      = (const float*)d_in[14];
    const float* conv_ng = (const float*)d_in[15];
    const float* conv_nb = (const float*)d_in[16];
    const float* pw1_w   = (const float*)d_in[17];
    const float* pw1_b   = (const float*)d_in[18];
    const float* dw_w    = (const float*)d_in[19];
    const float* dw_b    = (const float*)d_in[20];
    const float* bn_g    = (const float*)d_in[21];
    const float* bn_b    = (const float*)d_in[22];
    const float* bn_rm   = (const float*)d_in[23];
    const float* bn_rv   = (const float*)d_in[24];
    const float* pw2_w   = (const float*)d_in[25];
    const float* pw2_b   = (const float*)d_in[26];
    const float* ff2_ng  = (const float*)d_in[27];
    const float* ff2_nb  = (const float*)d_in[28];
    const float* ff2_w1  = (const float*)d_in[29];
    const float* ff2_b1  = (const float*)d_in[30];
    const float* ff2_w2  = (const float*)d_in[31];
    const float* ff2_b2  = (const float*)d_in[32];
    const float* fin_g   = (const float*)d_in[33];
    const float* fin_b   = (const float*)d_in[34];

    const int M = 8192;        // B*T
    char* ws = (char*)d_ws;
    size_t off = 0;
    auto alloc = [&](size_t bytes) {
        size_t o = off;
        off += (bytes + 255) & ~(size_t)255;
        return o;
    };
    // bf16 transposed weights [N][K]
    const size_t o_ff1w1 = alloc((size_t)4096 * 1024 * 2);
    const size_t o_ff1w2 = alloc((size_t)1024 * 4096 * 2);
    const size_t o_wq    = alloc((size_t)1024 * 1024 * 2);
    const size_t o_wkva  = alloc((size_t)256 * 1024 * 2);
    const size_t o_wkvb  = alloc((size_t)512 * 256 * 2);
    const size_t o_wo    = alloc((size_t)1024 * 1024 * 2);
    const size_t o_pw1   = alloc((size_t)2048 * 1024 * 2);
    const size_t o_pw2   = alloc((size_t)1024 * 1024 * 2);
    const size_t o_ff2w1 = alloc((size_t)4096 * 1024 * 2);
    const size_t o_ff2w2 = alloc((size_t)1024 * 4096 * 2);
    const size_t o_ctab  = alloc((size_t)1024 * 32 * 4);
    const size_t o_stab  = alloc((size_t)1024 * 32 * 4);
    const size_t o_xres  = alloc((size_t)M * 1024 * 4);     // fp32 running residual
    const size_t o_ln    = alloc((size_t)M * 1024 * 2);     // bf16 LN output
    const size_t o_bufa  = alloc((size_t)64 * 1024 * 1024); // big bf16 scratch
    if (ws_size < off) return;  // workspace too small -> clean failure signal

    // sub-offsets within BUFA
    u16* BUFA = (u16*)(ws + o_bufa);
    u16* Qb    = BUFA;                                   // 16 MB
    u16* KVb   = (u16*)((char*)BUFA + (16u << 20));      // 8 MB
    float* KVA = (float*)((char*)BUFA + (24u << 20));    // 8 MB fp32
    u16* LAT   = (u16*)((char*)BUFA + (32u << 20));      // 4 MB
    u16* VT    = (u16*)((char*)BUFA + (36u << 20));      // 4 MB
    u16* OB    = (u16*)((char*)BUFA + (40u << 20));      // 16 MB
    u16* PW1O  = BUFA;                                   // 32 MB (conv phase)
    u16* GLUO  = (u16*)((char*)BUFA + (32u << 20));      // 16 MB
    u16* CONVO = (u16*)((char*)BUFA + (48u << 20));      // 16 MB
    u16* HID   = BUFA;                                   // 64 MB (FFN phase)

    u16* WT_FF1W1 = (u16*)(ws + o_ff1w1);
    u16* WT_FF1W2 = (u16*)(ws + o_ff1w2);
    u16* WT_WQ    = (u16*)(ws + o_wq);
    u16* WT_WKVA  = (u16*)(ws + o_wkva);
    u16* WT_WKVB  = (u16*)(ws + o_wkvb);
    u16* WT_WO    = (u16*)(ws + o_wo);
    u16* WT_PW1   = (u16*)(ws + o_pw1);
    u16* WT_PW2   = (u16*)(ws + o_pw2);
    u16* WT_FF2W1 = (u16*)(ws + o_ff2w1);
    u16* WT_FF2W2 = (u16*)(ws + o_ff2w2);
    float* CT = (float*)(ws + o_ctab);
    float* ST = (float*)(ws + o_stab);
    float* XR = (float*)(ws + o_xres);
    u16* LNB  = (u16*)(ws + o_ln);

    // --- weight conversion (transpose to [N][K] bf16) ---
    wconvert_t<<<dim3(32, 128), 256, 0, stream>>>(ff1_w1, WT_FF1W1, 1024, 4096, 4096);
    wconvert_t<<<dim3(128, 32), 256, 0, stream>>>(ff1_w2, WT_FF1W2, 4096, 1024, 1024);
    wconvert_t<<<dim3(32, 32),  256, 0, stream>>>(wq,     WT_WQ,    1024, 1024, 1024);
    wconvert_t<<<dim3(32, 8),   256, 0, stream>>>(wkva,   WT_WKVA,  1024, 256,  320);
    wconvert_t<<<dim3(8, 16),   256, 0, stream>>>(wkvb,   WT_WKVB,  256,  512,  512);
    wconvert_t<<<dim3(32, 32),  256, 0, stream>>>(wo,     WT_WO,    1024, 1024, 1024);
    wconvert_t<<<dim3(32, 64),  256, 0, stream>>>(pw1_w,  WT_PW1,   1024, 2048, 2048);
    wconvert_t<<<dim3(32, 32),  256, 0, stream>>>(pw2_w,  WT_PW2,   1024, 1024, 1024);
    wconvert_t<<<dim3(32, 128), 256, 0, stream>>>(ff2_w1, WT_FF2W1, 1024, 4096, 4096);
    wconvert_t<<<dim3(128, 32), 256, 0, stream>>>(ff2_w2, WT_FF2W2, 4096, 1024, 1024);
    rope_tables_kernel<<<128, 256, 0, stream>>>(CT, ST);

    // --- FFN1 (macaron half) ---
    ln_kernel<0><<<M, 256, 0, stream>>>(x, ff1_ng, ff1_nb, LNB, 1024);
    gemm_bf16<1><<<dim3(32, 64), 256, 0, stream>>>(LNB, WT_FF1W1, ff1_b1, nullptr, 0.f, HID, M, 4096, 1024);
    gemm_bf16<3><<<dim3(8, 64), 256, 0, stream>>>(HID, WT_FF1W2, ff1_b2, x, 0.5f, XR, M, 1024, 4096);

    // --- attention (RMLA) ---
    ln_kernel<0><<<M, 256, 0, stream>>>(XR, attn_ng, attn_nb, LNB, 1024);
    gemm_bf16<0><<<dim3(8, 64), 256, 0, stream>>>(LNB, WT_WQ, nullptr, nullptr, 0.f, Qb, M, 1024, 1024);
    gemm_bf16<2><<<dim3(2, 64), 256, 0, stream>>>(LNB, WT_WKVA, nullptr, nullptr, 0.f, KVA, M, 256, 1024);
    ln_kernel<0><<<M, 256, 0, stream>>>(KVA, kvn_g, kvn_b, LAT, 256);
    gemm_bf16<0><<<dim3(4, 64), 256, 0, stream>>>(LAT, WT_WKVB, nullptr, nullptr, 0.f, KVb, M, 512, 256);
    rope_kernel<<<16384, 256, 0, stream>>>(Qb, CT, ST, 15, 4, 1024, 0.125f);  // fold 1/sqrt(64)
    rope_kernel<<<4096, 256, 0, stream>>>(KVb, CT, ST, 3, 2, 512, 1.0f);
    vtranspose_kernel<<<dim3(32, 2, 32), 256, 0, stream>>>(KVb, VT);
    attn_kernel<<<dim3(128, 16), 256, 0, stream>>>(Qb, KVb, VT, OB);
    gemm_bf16<3><<<dim3(8, 64), 256, 0, stream>>>(OB, WT_WO, nullptr, XR, 1.f, XR, M, 1024, 1024);

    // --- conv module ---
    ln_kernel<0><<<M, 256, 0, stream>>>(XR, conv_ng, conv_nb, LNB, 1024);
    gemm_bf16<0><<<dim3(16, 64), 256, 0, stream>>>(LNB, WT_PW1, pw1_b, nullptr, 0.f, PW1O, M, 2048, 1024);
    glu_kernel<<<32768, 256, 0, stream>>>(PW1O, GLUO);
    dwconv_kernel<<<dim3(4, 128, 8), 256, 0, stream>>>(GLUO, dw_w, dw_b, bn_g, bn_b, bn_rm, bn_rv, CONVO);
    gemm_bf16<3><<<dim3(8, 64), 256, 0, stream>>>(CONVO, WT_PW2, pw2_b, XR, 1.f, XR, M, 1024, 1024);

    // --- FFN2 (macaron half) ---
    ln_kernel<0><<<M, 256, 0, stream>>>(XR, ff2_ng, ff2_nb, LNB, 1024);
    gemm_bf16<1><<<dim3(32, 64), 256, 0, stream>>>(LNB, WT_FF2W1, ff2_b1, nullptr, 0.f, HID, M, 4096, 1024);
    gemm_bf16<3><<<dim3(8, 64), 256, 0, stream>>>(HID, WT_FF2W2, ff2_b2, XR, 0.5f, XR, M, 1024, 4096);

    // --- final LN -> d_out (fp32) ---
    ln_kernel<1><<<M, 256, 0, stream>>>(XR, fin_g, fin_b, d_out, 1024);
}

// Round 3
// 919.752 us; speedup vs baseline: 1.1963x; 1.1963x over previous
//
#include <hip/hip_runtime.h>
#include <stdint.h>

typedef unsigned short u16;
using bf16x8 = __attribute__((ext_vector_type(8))) __bf16;
using f32x4  = __attribute__((ext_vector_type(4))) float;

// ---------- helpers ----------
__device__ __forceinline__ u16 f2bf(float f) {
    uint32_t u = __float_as_uint(f);
    u += 0x7fffu + ((u >> 16) & 1u);          // round-to-nearest-even
    return (u16)(u >> 16);
}
__device__ __forceinline__ float bf2f(u16 u) {
    return __uint_as_float(((uint32_t)u) << 16);
}
__device__ __forceinline__ void gload16(const void* g, void* l) {
    // async global->LDS, 16B per lane; LDS dest = wave-uniform base + lane*16
    __builtin_amdgcn_global_load_lds(
        (__attribute__((address_space(1))) void*)(uintptr_t)g,
        (__attribute__((address_space(3))) void*)(uintptr_t)l,
        16, 0, 0);
}

// ---------- LayerNorm: fp32 in -> bf16 (mode 0) or fp32 (mode 1) out ----------
template <int OUTF32>
__global__ __launch_bounds__(256) void ln_kernel(const float* __restrict__ in,
                                                 const float* __restrict__ g,
                                                 const float* __restrict__ b,
                                                 void* __restrict__ out, int D) {
    const int row = blockIdx.x;
    const int tid = threadIdx.x;
    const float* x = in + (size_t)row * D;
    const int nv = D >> 8;                    // 4 for D=1024, 1 for D=256
    float v[4];
    float s1 = 0.f, s2 = 0.f;
    for (int i = 0; i < nv; ++i) {
        float t = x[tid + (i << 8)];
        v[i] = t; s1 += t; s2 += t * t;
    }
    for (int o = 1; o < 64; o <<= 1) {
        s1 += __shfl_xor(s1, o, 64);
        s2 += __shfl_xor(s2, o, 64);
    }
    __shared__ float r1[4], r2[4];
    const int w = tid >> 6;
    if ((tid & 63) == 0) { r1[w] = s1; r2[w] = s2; }
    __syncthreads();
    s1 = r1[0] + r1[1] + r1[2] + r1[3];
    s2 = r2[0] + r2[1] + r2[2] + r2[3];
    const float mean = s1 / (float)D;
    const float var  = s2 / (float)D - mean * mean;
    const float inv  = rsqrtf(var + 1e-5f);
    for (int i = 0; i < nv; ++i) {
        int c = tid + (i << 8);
        float y = (v[i] - mean) * inv * g[c] + b[c];
        if (OUTF32) ((float*)out)[(size_t)row * D + c] = y;
        else        ((u16*)out)[(size_t)row * D + c] = f2bf(y);
    }
}

// ---------- weight transpose + fp32->bf16 convert: W[K][ldw](first N cols) -> Wt[N][K] ----------
__global__ __launch_bounds__(256) void wconvert_t(const float* __restrict__ W,
                                                  u16* __restrict__ Wt,
                                                  int K, int N, int ldw) {
    __shared__ float tile[32][33];
    const int k0 = blockIdx.x * 32, n0 = blockIdx.y * 32;
    const int tx = threadIdx.x & 31, ty = threadIdx.x >> 5;  // 32 x 8
    for (int i = 0; i < 4; ++i)
        tile[ty + i * 8][tx] = W[(size_t)(k0 + ty + i * 8) * ldw + n0 + tx];
    __syncthreads();
    for (int i = 0; i < 4; ++i)
        Wt[(size_t)(n0 + ty + i * 8) * K + k0 + tx] = f2bf(tile[tx][ty + i * 8]);
}

// ---------- GEMM: C[M,N] = A[M,K](bf16) * Bt[N,K](bf16)^T, 128x128 tile, BK=32 ----------
// EPI: 0 = bf16 out (+bias) ; 1 = silu -> bf16 (+bias) ; 2 = f32 out (+bias) ;
//      3 = f32 out = res + rscale*(acc+bias)
template <int EPI>
__global__ __launch_bounds__(256) void gemm_bf16(const u16* __restrict__ A,
                                                 const u16* __restrict__ Bt,
                                                 const float* __restrict__ bias,
                                                 const float* __restrict__ res,
                                                 float rscale,
                                                 void* __restrict__ outp,
                                                 int M, int N, int K) {
    __shared__ u16 sA[128 * 32];
    __shared__ u16 sB[128 * 32];
    const int tid = threadIdx.x;
    const int lane = tid & 63;
    const int w = tid >> 6;
    const int wm = w >> 1, wn = w & 1;        // 2x2 wave grid
    const int fr = lane & 15, fq = lane >> 4;
    const int bm0 = blockIdx.y * 128, bn0 = blockIdx.x * 128;

    f32x4 acc[4][4] = {};

    const u16* ga0 = A  + (size_t)(bm0 + (tid >> 2)) * K + ((tid & 3) << 3);
    const u16* gb0 = Bt + (size_t)(bn0 + (tid >> 2)) * K + ((tid & 3) << 3);
    const size_t rstep = (size_t)64 * K;
    u16* la0 = sA + ((tid >> 6) << 9);        // wave-uniform base (w*512 elems)
    u16* lb0 = sB + ((tid >> 6) << 9);

    for (int kt = 0; kt < K; kt += 32) {
        __syncthreads();
        gload16(ga0 + kt,         la0);
        gload16(ga0 + rstep + kt, la0 + 2048);
        gload16(gb0 + kt,         lb0);
        gload16(gb0 + rstep + kt, lb0 + 2048);
        __syncthreads();
        bf16x8 afr[4], bfr[4];
        const u16* pa = sA + (wm * 64 + fr) * 32 + fq * 8;
        const u16* pb = sB + (wn * 64 + fr) * 32 + fq * 8;
#pragma unroll
        for (int i = 0; i < 4; ++i) {
            afr[i] = *(const bf16x8*)(pa + i * 512);
            bfr[i] = *(const bf16x8*)(pb + i * 512);
        }
#pragma unroll
        for (int mi = 0; mi < 4; ++mi)
#pragma unroll
            for (int ni = 0; ni < 4; ++ni)
                acc[mi][ni] = __builtin_amdgcn_mfma_f32_16x16x32_bf16(
                    afr[mi], bfr[ni], acc[mi][ni], 0, 0, 0);
    }

    // epilogue: D row=(lane>>4)*4+reg, col=lane&15 within each 16x16 frag
#pragma unroll
    for (int mi = 0; mi < 4; ++mi) {
#pragma unroll
        for (int ni = 0; ni < 4; ++ni) {
            const int r0 = bm0 + wm * 64 + mi * 16 + fq * 4;
            const int c  = bn0 + wn * 64 + ni * 16 + fr;
            const float bv = bias ? bias[c] : 0.f;
#pragma unroll
            for (int r = 0; r < 4; ++r) {
                float v = acc[mi][ni][r] + bv;
                const size_t idx = (size_t)(r0 + r) * N + c;
                if (EPI == 0) {
                    ((u16*)outp)[idx] = f2bf(v);
                } else if (EPI == 1) {
                    v = v / (1.f + __expf(-v));           // silu
                    ((u16*)outp)[idx] = f2bf(v);
                } else if (EPI == 2) {
                    ((float*)outp)[idx] = v;
                } else {
                    ((float*)outp)[idx] = res[idx] + rscale * v;
                }
            }
        }
    }
}

// ---------- RoPE tables: ctab/stab [T=1024][32] ----------
__global__ __launch_bounds__(256) void rope_tables_kernel(float* __restrict__ ct,
                                                          float* __restrict__ st) {
    const int i = blockIdx.x * 256 + threadIdx.x;   // 32768
    const int t = i >> 5, j = i & 31;
    const float inv = powf(10000.f, -(float)j / 32.f);
    const float f = (float)t * inv;
    ct[i] = cosf(f);
    st[i] = sinf(f);
}

// ---------- RoPE apply in place on bf16, optional output scale ----------
__global__ __launch_bounds__(256) void rope_kernel(u16* __restrict__ buf,
                                                   const float* __restrict__ ct,
                                                   const float* __restrict__ st,
                                                   int hmask, int hshift, int rstride,
                                                   float scale) {
    const int i = blockIdx.x * 256 + threadIdx.x;
    const int j = i & 31;
    const int hh = (i >> 5) & hmask;
    const int m = i >> (5 + hshift);
    const int t = m & 1023;
    u16* p = buf + (size_t)m * rstride + hh * 64 + j;
    const float c = ct[t * 32 + j], s = st[t * 32 + j];
    const float x1 = bf2f(p[0]), x2 = bf2f(p[32]);
    p[0]  = f2bf((x1 * c - x2 * s) * scale);
    p[32] = f2bf((x2 * c + x1 * s) * scale);
}

// ---------- V transpose: KV[(b*1024+t)*512 + 256 + kh*64 + hd] -> Vt[(b*4+kh)*64+hd][t] ----------
__global__ __launch_bounds__(256) void vtranspose_kernel(const u16* __restrict__ KV,
                                                         u16* __restrict__ Vt) {
    __shared__ u16 tile[32][33];
    const int t0 = blockIdx.x * 32, h0 = blockIdx.y * 32;
    const int bk = blockIdx.z;                 // b*4 + kh
    const int b = bk >> 2, kh = bk & 3;
    const int tx = threadIdx.x & 31, ty = threadIdx.x >> 5;
    for (int i = 0; i < 4; ++i)
        tile[ty + i * 8][tx] =
            KV[(size_t)(b * 1024 + t0 + ty + i * 8) * 512 + 256 + kh * 64 + h0 + tx];
    __syncthreads();
    for (int i = 0; i < 4; ++i)
        Vt[((size_t)bk * 64 + h0 + ty + i * 8) * 1024 + t0 + tx] = tile[tx][ty + i * 8];
}

// ---------- fused SDPA v3: LDS-staged K/V shared by the 4 GQA heads ----------
// Block = (b*4+kh, qtile16). 4 waves = the 4 heads h = kh*4+w of the GQA group,
// each owning 16 q-rows. K/V tiles [64 kv][64 hd] staged in LDS via
// global_load_lds (double-buffered, 2-phase), 3-bit XOR swizzle applied on
// the PRE-SWIZZLED GLOBAL SOURCE + the ds_read address (LDS dest linear).
// Softmax in-lane (swapped QK^T), P in wave-private swizzled LDS slab.
__global__ __launch_bounds__(256) void attn_kernel(const u16* __restrict__ Q,
                                                   const u16* __restrict__ KV,
                                                   const u16* __restrict__ Vt,
                                                   u16* __restrict__ O) {
    __shared__ __align__(16) u16 sK[2][64 * 64];
    __shared__ __align__(16) u16 sV[2][64 * 64];
    __shared__ __align__(16) u16 sP[4][16 * 64];
    const int tid = threadIdx.x, lane = tid & 63, w = tid >> 6;
    const int fr = lane & 15, fq = lane >> 4, frx = fr & 7;
    const int bk = blockIdx.x, b = bk >> 2, kh = bk & 3;
    const int h = kh * 4 + w;
    const int q0 = blockIdx.y * 16;
    const int qrow = b * 1024 + q0 + fr;

    // --- per-lane staging source (pre-swizzled slot; row&7 == (lane>>3)&7) ---
    const int srow = w * 16 + (lane >> 3);                 // 8 rows per gload16
    const int sslot = (lane & 7) ^ ((lane >> 3) & 7);
    const u16* gK = KV + (size_t)(b * 1024 + srow) * 512 + kh * 64 + sslot * 8;
    const u16* gV = Vt + (size_t)((b * 4 + kh) * 64 + srow) * 1024 + sslot * 8;
    u16* dK = (u16*)sK + w * 16 * 64;                      // wave-uniform LDS bases
    u16* dV = (u16*)sV + w * 16 * 64;

    bf16x8 qf[2];
    qf[0] = *(const bf16x8*)(Q + (size_t)qrow * 1024 + h * 64 + fq * 8);
    qf[1] = *(const bf16x8*)(Q + (size_t)qrow * 1024 + h * 64 + 32 + fq * 8);

    f32x4 oacc[4] = {};
    float mrun = -1e30f, lrun = 0.f;
    u16* sPw = sP[w];

    // prologue: stage tile 0 into buf 0
    gload16(gK, dK);
    gload16(gK + (size_t)8 * 512, dK + 8 * 64);
    gload16(gV, dV);
    gload16(gV + (size_t)8 * 1024, dV + 8 * 64);
    __syncthreads();                                       // drains vmcnt + barrier

    int cur = 0;
    for (int t = 0; t < 16; ++t) {
        const int kv0 = t * 64;
        // ---- stage next tile into buf[cur^1] (overlaps with compute below) ----
        if (t < 15) {
            const int kn = kv0 + 64;
            const int nx = (cur ^ 1) * 4096;
            gload16(gK + (size_t)kn * 512,       dK + nx);
            gload16(gK + (size_t)(kn + 8) * 512, dK + nx + 8 * 64);
            gload16(gV + kn,                     dV + nx);
            gload16(gV + kn + (size_t)8 * 1024,  dV + nx + 8 * 64);
        }
        const u16* sKc = (u16*)sK + cur * 4096;
        const u16* sVc = (u16*)sV + cur * 4096;
        // ---- S^T = K x Q^T (Q pre-scaled by 1/8 in rope) ----
        f32x4 sacc[4] = {};
#pragma unroll
        for (int ks = 0; ks < 2; ++ks)
#pragma unroll
            for (int nb = 0; nb < 4; ++nb) {
                const bf16x8 kf = *(const bf16x8*)(
                    sKc + (nb * 16 + fr) * 64 + (((ks * 4 + fq) ^ frx) << 3));
                sacc[nb] = __builtin_amdgcn_mfma_f32_16x16x32_bf16(kf, qf[ks], sacc[nb], 0, 0, 0);
            }
        // ---- in-lane max over 16 kv, then reduce across the 4 fq lanes ----
        float pm;
        {
            float a0 = fmaxf(fmaxf(sacc[0][0], sacc[0][1]), fmaxf(sacc[0][2], sacc[0][3]));
            float a1 = fmaxf(fmaxf(sacc[1][0], sacc[1][1]), fmaxf(sacc[1][2], sacc[1][3]));
            float a2 = fmaxf(fmaxf(sacc[2][0], sacc[2][1]), fmaxf(sacc[2][2], sacc[2][3]));
            float a3 = fmaxf(fmaxf(sacc[3][0], sacc[3][1]), fmaxf(sacc[3][2], sacc[3][3]));
            pm = fmaxf(fmaxf(a0, a1), fmaxf(a2, a3));
        }
        pm = fmaxf(pm, __shfl_xor(pm, 16, 64));
        pm = fmaxf(pm, __shfl_xor(pm, 32, 64));
        // ---- T13: rescale only when max grew past threshold ----
        if (!__all(pm <= mrun + 8.f)) {
            const float mn = fmaxf(mrun, pm);
            const float al = __expf(mrun - mn);
            mrun = mn;
            lrun *= al;
#pragma unroll
            for (int f = 0; f < 4; ++f) {
                f32x4 tt = oacc[f];
#pragma unroll
                for (int r = 0; r < 4; ++r) tt[r] *= al;
                oacc[f] = tt;
            }
        }
        // ---- P = exp(S - m), in-lane rowsum, pack to swizzled LDS slab ----
        float rs = 0.f;
#pragma unroll
        for (int nb = 0; nb < 4; ++nb) {
            union { uint2 u2; u16 hh[4]; } pk;
#pragma unroll
            for (int r = 0; r < 4; ++r) {
                const float p = __expf(sacc[nb][r] - mrun);
                rs += p;
                pk.hh[r] = f2bf(p);
            }
            const int slotl = nb * 2 + (fq >> 1);
            *(uint2*)(sPw + fr * 64 + (((slotl ^ frx) << 3) | ((fq & 1) << 2))) = pk.u2;
        }
        rs += __shfl_xor(rs, 16, 64);
        rs += __shfl_xor(rs, 32, 64);
        lrun += rs;
        // wave-local P write->read ordering (rule #18: drain + sched fence)
        asm volatile("s_waitcnt lgkmcnt(0)" ::: "memory");
        __builtin_amdgcn_sched_barrier(0);
        // ---- O^T += V^T x P^T ----
#pragma unroll
        for (int ks2 = 0; ks2 < 2; ++ks2) {
            const bf16x8 pf = *(const bf16x8*)(
                sPw + fr * 64 + (((ks2 * 4 + fq) ^ frx) << 3));
#pragma unroll
            for (int f = 0; f < 4; ++f) {
                const bf16x8 vf = *(const bf16x8*)(
                    sVc + (f * 16 + fr) * 64 + (((ks2 * 4 + fq) ^ frx) << 3));
                oacc[f] = __builtin_amdgcn_mfma_f32_16x16x32_bf16(vf, pf, oacc[f], 0, 0, 0);
            }
        }
        __syncthreads();                                   // drains vmcnt (next tile ready)
        cur ^= 1;
    }

    const float linv = 1.f / lrun;
#pragma unroll
    for (int f = 0; f < 4; ++f) {
        union { uint2 u2; u16 hh[4]; } ok;
#pragma unroll
        for (int r = 0; r < 4; ++r) ok.hh[r] = f2bf(oacc[f][r] * linv);
        *(uint2*)(O + (size_t)qrow * 1024 + h * 64 + f * 16 + fq * 4) = ok.u2;
    }
}

// ---------- GLU: in [M,2048] bf16 -> out [M,1024] bf16 ----------
__global__ __launch_bounds__(256) void glu_kernel(const u16* __restrict__ in,
                                                  u16* __restrict__ out) {
    const size_t i = (size_t)blockIdx.x * 256 + threadIdx.x;  // 8192*1024 total
    const size_t m = i >> 10;
    const int j = (int)(i & 1023);
    const float a = bf2f(in[m * 2048 + j]);
    const float g = bf2f(in[m * 2048 + 1024 + j]);
    out[i] = f2bf(a / (1.f + __expf(-g)));
}

// ---------- depthwise conv(K=31) + BN + SiLU: [B,T,D] bf16 -> bf16 ----------
__global__ __launch_bounds__(256) void dwconv_kernel(const u16* __restrict__ G,
                                                     const float* __restrict__ wt,
                                                     const float* __restrict__ wb,
                                                     const float* __restrict__ bg,
                                                     const float* __restrict__ bb,
                                                     const float* __restrict__ rm,
                                                     const float* __restrict__ rv,
                                                     u16* __restrict__ out) {
    __shared__ u16 sg[38 * 256];
    const int tid = threadIdx.x;
    const int d = blockIdx.x * 256 + tid;
    const int t0 = blockIdx.y * 8;
    const int b = blockIdx.z;
    const size_t base = (size_t)b * 1024 * 1024 + d;
    for (int i = 0; i < 38; ++i) {
        const int t = t0 - 15 + i;
        sg[i * 256 + tid] = (t >= 0 && t < 1024) ? G[base + (size_t)t * 1024] : (u16)0;
    }
    __syncthreads();
    float wreg[31];
#pragma unroll
    for (int k = 0; k < 31; ++k) wreg[k] = wt[d * 31 + k];
    const float scale = bg[d] * rsqrtf(rv[d] + 1e-5f);
    const float addv = wb[d] - rm[d];
#pragma unroll
    for (int j = 0; j < 8; ++j) {
        float acc = 0.f;
#pragma unroll
        for (int k = 0; k < 31; ++k) acc += bf2f(sg[(j + k) * 256 + tid]) * wreg[k];
        float y = (acc + addv) * scale + bb[d];
        y = y / (1.f + __expf(-y));               // silu
        out[base + (size_t)(t0 + j) * 1024] = f2bf(y);
    }
}

// =====================================================================
extern "C" void kernel_launch(void* const* d_in, const int* in_sizes, int n_in,
                              void* d_out, int out_size, void* d_ws, size_t ws_size,
                              hipStream_t stream) {
    (void)in_sizes; (void)n_in; (void)out_size;

    const float* x       = (const float*)d_in[0];
    const float* ff1_ng  = (const float*)d_in[1];
    const float* ff1_nb  = (const float*)d_in[2];
    const float* ff1_w1  = (const float*)d_in[3];
    const float* ff1_b1  = (const float*)d_in[4];
    const float* ff1_w2  = (const float*)d_in[5];
    const float* ff1_b2  = (const float*)d_in[6];
    const float* attn_ng = (const float*)d_in[7];
    const float* attn_nb = (const float*)d_in[8];
    const float* wq      = (const float*)d_in[9];
    const float* wkva    = (const float*)d_in[10];
    const float* kvn_g   = (const float*)d_in[11];
    const float* kvn_b   = (const float*)d_in[12];
    const float* wkvb    = (const float*)d_in[13];
    const float* wo      = (const float*)d_in[14];
    const float* conv_ng = (const float*)d_in[15];
    const float* conv_nb = (const float*)d_in[16];
    const float* pw1_w   = (const float*)d_in[17];
    const float* pw1_b   = (const float*)d_in[18];
    const float* dw_w    = (const float*)d_in[19];
    const float* dw_b    = (const float*)d_in[20];
    const float* bn_g    = (const float*)d_in[21];
    const float* bn_b    = (const float*)d_in[22];
    const float* bn_rm   = (const float*)d_in[23];
    const float* bn_rv   = (const float*)d_in[24];
    const float* pw2_w   = (const float*)d_in[25];
    const float* pw2_b   = (const float*)d_in[26];
    const float* ff2_ng  = (const float*)d_in[27];
    const float* ff2_nb  = (const float*)d_in[28];
    const float* ff2_w1  = (const float*)d_in[29];
    const float* ff2_b1  = (const float*)d_in[30];
    const float* ff2_w2  = (const float*)d_in[31];
    const float* ff2_b2  = (const float*)d_in[32];
    const float* fin_g   = (const float*)d_in[33];
    const float* fin_b   = (const float*)d_in[34];

    const int M = 8192;        // B*T
    char* ws = (char*)d_ws;
    size_t off = 0;
    auto alloc = [&](size_t bytes) {
        size_t o = off;
        off += (bytes + 255) & ~(size_t)255;
        return o;
    };
    // bf16 transposed weights [N][K]
    const size_t o_ff1w1 = alloc((size_t)4096 * 1024 * 2);
    const size_t o_ff1w2 = alloc((size_t)1024 * 4096 * 2);
    const size_t o_wq    = alloc((size_t)1024 * 1024 * 2);
    const size_t o_wkva  = alloc((size_t)256 * 1024 * 2);
    const size_t o_wkvb  = alloc((size_t)512 * 256 * 2);
    const size_t o_wo    = alloc((size_t)1024 * 1024 * 2);
    const size_t o_pw1   = alloc((size_t)2048 * 1024 * 2);
    const size_t o_pw2   = alloc((size_t)1024 * 1024 * 2);
    const size_t o_ff2w1 = alloc((size_t)4096 * 1024 * 2);
    const size_t o_ff2w2 = alloc((size_t)1024 * 4096 * 2);
    const size_t o_ctab  = alloc((size_t)1024 * 32 * 4);
    const size_t o_stab  = alloc((size_t)1024 * 32 * 4);
    const size_t o_xres  = alloc((size_t)M * 1024 * 4);     // fp32 running residual
    const size_t o_ln    = alloc((size_t)M * 1024 * 2);     // bf16 LN output
    const size_t o_bufa  = alloc((size_t)64 * 1024 * 1024); // big bf16 scratch
    if (ws_size < off) return;  // workspace too small -> clean failure signal

    // sub-offsets within BUFA
    u16* BUFA = (u16*)(ws + o_bufa);
    u16* Qb    = BUFA;                                   // 16 MB
    u16* KVb   = (u16*)((char*)BUFA + (16u << 20));      // 8 MB
    float* KVA = (float*)((char*)BUFA + (24u << 20));    // 8 MB fp32
    u16* LAT   = (u16*)((char*)BUFA + (32u << 20));      // 4 MB
    u16* VT    = (u16*)((char*)BUFA + (36u << 20));      // 4 MB
    u16* OB    = (u16*)((char*)BUFA + (40u << 20));      // 16 MB
    u16* PW1O  = BUFA;                                   // 32 MB (conv phase)
    u16* GLUO  = (u16*)((char*)BUFA + (32u << 20));      // 16 MB
    u16* CONVO = (u16*)((char*)BUFA + (48u << 20));      // 16 MB
    u16* HID   = BUFA;                                   // 64 MB (FFN phase)

    u16* WT_FF1W1 = (u16*)(ws + o_ff1w1);
    u16* WT_FF1W2 = (u16*)(ws + o_ff1w2);
    u16* WT_WQ    = (u16*)(ws + o_wq);
    u16* WT_WKVA  = (u16*)(ws + o_wkva);
    u16* WT_WKVB  = (u16*)(ws + o_wkvb);
    u16* WT_WO    = (u16*)(ws + o_wo);
    u16* WT_PW1   = (u16*)(ws + o_pw1);
    u16* WT_PW2   = (u16*)(ws + o_pw2);
    u16* WT_FF2W1 = (u16*)(ws + o_ff2w1);
    u16* WT_FF2W2 = (u16*)(ws + o_ff2w2);
    float* CT = (float*)(ws + o_ctab);
    float* ST = (float*)(ws + o_stab);
    float* XR = (float*)(ws + o_xres);
    u16* LNB  = (u16*)(ws + o_ln);

    // --- weight conversion (transpose to [N][K] bf16) ---
    wconvert_t<<<dim3(32, 128), 256, 0, stream>>>(ff1_w1, WT_FF1W1, 1024, 4096, 4096);
    wconvert_t<<<dim3(128, 32), 256, 0, stream>>>(ff1_w2, WT_FF1W2, 4096, 1024, 1024);
    wconvert_t<<<dim3(32, 32),  256, 0, stream>>>(wq,     WT_WQ,    1024, 1024, 1024);
    wconvert_t<<<dim3(32, 8),   256, 0, stream>>>(wkva,   WT_WKVA,  1024, 256,  320);
    wconvert_t<<<dim3(8, 16),   256, 0, stream>>>(wkvb,   WT_WKVB,  256,  512,  512);
    wconvert_t<<<dim3(32, 32),  256, 0, stream>>>(wo,     WT_WO,    1024, 1024, 1024);
    wconvert_t<<<dim3(32, 64),  256, 0, stream>>>(pw1_w,  WT_PW1,   1024, 2048, 2048);
    wconvert_t<<<dim3(32, 32),  256, 0, stream>>>(pw2_w,  WT_PW2,   1024, 1024, 1024);
    wconvert_t<<<dim3(32, 128), 256, 0, stream>>>(ff2_w1, WT_FF2W1, 1024, 4096, 4096);
    wconvert_t<<<dim3(128, 32), 256, 0, stream>>>(ff2_w2, WT_FF2W2, 4096, 1024, 1024);
    rope_tables_kernel<<<128, 256, 0, stream>>>(CT, ST);

    // --- FFN1 (macaron half) ---
    ln_kernel<0><<<M, 256, 0, stream>>>(x, ff1_ng, ff1_nb, LNB, 1024);
    gemm_bf16<1><<<dim3(32, 64), 256, 0, stream>>>(LNB, WT_FF1W1, ff1_b1, nullptr, 0.f, HID, M, 4096, 1024);
    gemm_bf16<3><<<dim3(8, 64), 256, 0, stream>>>(HID, WT_FF1W2, ff1_b2, x, 0.5f, XR, M, 1024, 4096);

    // --- attention (RMLA) ---
    ln_kernel<0><<<M, 256, 0, stream>>>(XR, attn_ng, attn_nb, LNB, 1024);
    gemm_bf16<0><<<dim3(8, 64), 256, 0, stream>>>(LNB, WT_WQ, nullptr, nullptr, 0.f, Qb, M, 1024, 1024);
    gemm_bf16<2><<<dim3(2, 64), 256, 0, stream>>>(LNB, WT_WKVA, nullptr, nullptr, 0.f, KVA, M, 256, 1024);
    ln_kernel<0><<<M, 256, 0, stream>>>(KVA, kvn_g, kvn_b, LAT, 256);
    gemm_bf16<0><<<dim3(4, 64), 256, 0, stream>>>(LAT, WT_WKVB, nullptr, nullptr, 0.f, KVb, M, 512, 256);
    rope_kernel<<<16384, 256, 0, stream>>>(Qb, CT, ST, 15, 4, 1024, 0.125f);  // fold 1/sqrt(64)
    rope_kernel<<<4096, 256, 0, stream>>>(KVb, CT, ST, 3, 2, 512, 1.0f);
    vtranspose_kernel<<<dim3(32, 2, 32), 256, 0, stream>>>(KVb, VT);
    attn_kernel<<<dim3(32, 64), 256, 0, stream>>>(Qb, KVb, VT, OB);
    gemm_bf16<3><<<dim3(8, 64), 256, 0, stream>>>(OB, WT_WO, nullptr, XR, 1.f, XR, M, 1024, 1024);

    // --- conv module ---
    ln_kernel<0><<<M, 256, 0, stream>>>(XR, conv_ng, conv_nb, LNB, 1024);
    gemm_bf16<0><<<dim3(16, 64), 256, 0, stream>>>(LNB, WT_PW1, pw1_b, nullptr, 0.f, PW1O, M, 2048, 1024);
    glu_kernel<<<32768, 256, 0, stream>>>(PW1O, GLUO);
    dwconv_kernel<<<dim3(4, 128, 8), 256, 0, stream>>>(GLUO, dw_w, dw_b, bn_g, bn_b, bn_rm, bn_rv, CONVO);
    gemm_bf16<3><<<dim3(8, 64), 256, 0, stream>>>(CONVO, WT_PW2, pw2_b, XR, 1.f, XR, M, 1024, 1024);

    // --- FFN2 (macaron half) ---
    ln_kernel<0><<<M, 256, 0, stream>>>(XR, ff2_ng, ff2_nb, LNB, 1024);
    gemm_bf16<1><<<dim3(32, 64), 256, 0, stream>>>(LNB, WT_FF2W1, ff2_b1, nullptr, 0.f, HID, M, 4096, 1024);
    gemm_bf16<3><<<dim3(8, 64), 256, 0, stream>>>(HID, WT_FF2W2, ff2_b2, XR, 0.5f, XR, M, 1024, 4096);

    // --- final LN -> d_out (fp32) ---
    ln_kernel<1><<<M, 256, 0, stream>>>(XR, fin_g, fin_b, d_out, 1024);
}

// Round 4
// 809.917 us; speedup vs baseline: 1.3585x; 1.1356x over previous
//
#include <hip/hip_runtime.h>
#include <stdint.h>

typedef unsigned short u16;
using bf16x8 = __attribute__((ext_vector_type(8))) __bf16;
using f32x4  = __attribute__((ext_vector_type(4))) float;

// ---------- helpers ----------
__device__ __forceinline__ u16 f2bf(float f) {
    uint32_t u = __float_as_uint(f);
    u += 0x7fffu + ((u >> 16) & 1u);          // round-to-nearest-even
    return (u16)(u >> 16);
}
__device__ __forceinline__ float bf2f(u16 u) {
    return __uint_as_float(((uint32_t)u) << 16);
}
__device__ __forceinline__ void gload16(const void* g, void* l) {
    // async global->LDS, 16B per lane; LDS dest = wave-uniform base + lane*16
    __builtin_amdgcn_global_load_lds(
        (__attribute__((address_space(1))) void*)(uintptr_t)g,
        (__attribute__((address_space(3))) void*)(uintptr_t)l,
        16, 0, 0);
}

// ---------- LayerNorm: fp32 in -> bf16 (mode 0) or fp32 (mode 1) out ----------
template <int OUTF32>
__global__ __launch_bounds__(256) void ln_kernel(const float* __restrict__ in,
                                                 const float* __restrict__ g,
                                                 const float* __restrict__ b,
                                                 void* __restrict__ out, int D) {
    const int row = blockIdx.x;
    const int tid = threadIdx.x;
    const float* x = in + (size_t)row * D;
    const int nv = D >> 8;                    // 4 for D=1024, 1 for D=256
    float v[4];
    float s1 = 0.f, s2 = 0.f;
    for (int i = 0; i < nv; ++i) {
        float t = x[tid + (i << 8)];
        v[i] = t; s1 += t; s2 += t * t;
    }
    for (int o = 1; o < 64; o <<= 1) {
        s1 += __shfl_xor(s1, o, 64);
        s2 += __shfl_xor(s2, o, 64);
    }
    __shared__ float r1[4], r2[4];
    const int w = tid >> 6;
    if ((tid & 63) == 0) { r1[w] = s1; r2[w] = s2; }
    __syncthreads();
    s1 = r1[0] + r1[1] + r1[2] + r1[3];
    s2 = r2[0] + r2[1] + r2[2] + r2[3];
    const float mean = s1 / (float)D;
    const float var  = s2 / (float)D - mean * mean;
    const float inv  = rsqrtf(var + 1e-5f);
    for (int i = 0; i < nv; ++i) {
        int c = tid + (i << 8);
        float y = (v[i] - mean) * inv * g[c] + b[c];
        if (OUTF32) ((float*)out)[(size_t)row * D + c] = y;
        else        ((u16*)out)[(size_t)row * D + c] = f2bf(y);
    }
}

// ---------- weight transpose + fp32->bf16 convert: W[K][ldw](first N cols) -> Wt[N][K] ----------
// GLUPERM=1: output row n sources W column (n&1)*1024 + (n>>1)  (a/gate interleave for pw1)
template <int GLUPERM>
__global__ __launch_bounds__(256) void wconvert_t(const float* __restrict__ W,
                                                  u16* __restrict__ Wt,
                                                  int K, int N, int ldw) {
    __shared__ float tile[32][33];
    const int k0 = blockIdx.x * 32, n0 = blockIdx.y * 32;
    const int tx = threadIdx.x & 31, ty = threadIdx.x >> 5;  // 32 x 8
    const int csrc = GLUPERM ? ((tx & 1) * 1024 + (n0 >> 1) + (tx >> 1)) : (n0 + tx);
    for (int i = 0; i < 4; ++i)
        tile[ty + i * 8][tx] = W[(size_t)(k0 + ty + i * 8) * ldw + csrc];
    __syncthreads();
    for (int i = 0; i < 4; ++i)
        Wt[(size_t)(n0 + ty + i * 8) * K + k0 + tx] = f2bf(tile[tx][ty + i * 8]);
}

// ---------- GEMM v2: C[M,N] = A[M,K](bf16) * Bt[N,K](bf16)^T ----------
// 128x128 tile, BK=64, XOR-swizzled LDS (pre-swizzled global src + swizzled
// ds_read, linear gload_lds dest), swapped-operand MFMA (lane holds 4
// consecutive N-cols -> packed 8B/16B epilogue stores), XCD-chunked blockIdx.
// EPI: 0 = bf16 out (+bias) ; 1 = silu -> bf16 (+bias) ; 2 = f32 out (+bias) ;
//      3 = f32 out = res + rscale*(acc+bias) ; 4 = GLU pairs -> bf16 [M][N/2]
template <int EPI>
__global__ __launch_bounds__(256) void gemm_bf16(const u16* __restrict__ A,
                                                 const u16* __restrict__ Bt,
                                                 const float* __restrict__ bias,
                                                 const float* __restrict__ res,
                                                 float rscale,
                                                 void* __restrict__ outp,
                                                 int M, int N, int K, int nbx) {
    __shared__ u16 sA[128 * 64];
    __shared__ u16 sB[128 * 64];
    const int tid = threadIdx.x;
    const int lane = tid & 63;
    const int w = tid >> 6;
    const int wm = w >> 1, wn = w & 1;        // 2x2 wave grid
    const int fr = lane & 15, fq = lane >> 4, frx = fr & 7;
    // XCD-aware bijective swizzle (gridDim.x % 8 == 0 at all call sites)
    const int cpx = gridDim.x >> 3;
    const int lid = (blockIdx.x & 7) * cpx + (blockIdx.x >> 3);
    const int bn0 = (lid % nbx) * 128;
    const int bm0 = (lid / nbx) * 128;

    f32x4 acc[4][4] = {};

    // staging source: lane covers row w*8+lrow (8 lanes/row), pre-swizzled slot
    const int lrow = lane >> 3;
    const int lslot = (lane & 7) ^ lrow;
    const u16* ga0 = A  + (size_t)(bm0 + w * 8 + lrow) * K + lslot * 8;
    const u16* gb0 = Bt + (size_t)(bn0 + w * 8 + lrow) * K + lslot * 8;
    u16* la0 = sA + w * 512;                  // wave-uniform LDS bases
    u16* lb0 = sB + w * 512;
    const size_t rstep32 = (size_t)32 * K;

    for (int kt = 0; kt < K; kt += 64) {
        __syncthreads();                      // previous iter's reads done
#pragma unroll
        for (int i = 0; i < 4; ++i) {
            gload16(ga0 + kt + i * rstep32, la0 + i * 2048);
            gload16(gb0 + kt + i * rstep32, lb0 + i * 2048);
        }
        __syncthreads();                      // drains vmcnt: tile ready
#pragma unroll
        for (int kk = 0; kk < 2; ++kk) {
            bf16x8 afr[4], bfr[4];
            const int sl = (((kk * 4 + fq) ^ frx) << 3);
#pragma unroll
            for (int i = 0; i < 4; ++i) {
                afr[i] = *(const bf16x8*)(sA + (wm * 64 + i * 16 + fr) * 64 + sl);
                bfr[i] = *(const bf16x8*)(sB + (wn * 64 + i * 16 + fr) * 64 + sl);
            }
#pragma unroll
            for (int mi = 0; mi < 4; ++mi)
#pragma unroll
                for (int ni = 0; ni < 4; ++ni)
                    acc[mi][ni] = __builtin_amdgcn_mfma_f32_16x16x32_bf16(
                        bfr[ni], afr[mi], acc[mi][ni], 0, 0, 0);   // swapped: D[n][m]
        }
    }

    // epilogue: lane holds rows m=...+fr, cols n0..n0+3 (n0 = ...+fq*4)
#pragma unroll
    for (int mi = 0; mi < 4; ++mi) {
        const int m = bm0 + wm * 64 + mi * 16 + fr;
#pragma unroll
        for (int ni = 0; ni < 4; ++ni) {
            const int n0 = bn0 + wn * 64 + ni * 16 + fq * 4;
            if (EPI == 0 || EPI == 1) {
                union { uint2 u2; u16 hh[4]; } ok;
#pragma unroll
                for (int r = 0; r < 4; ++r) {
                    float v = acc[mi][ni][r] + (bias ? bias[n0 + r] : 0.f);
                    if (EPI == 1) v = v / (1.f + __expf(-v));
                    ok.hh[r] = f2bf(v);
                }
                *(uint2*)((u16*)outp + (size_t)m * N + n0) = ok.u2;
            } else if (EPI == 2) {
                f32x4 v;
#pragma unroll
                for (int r = 0; r < 4; ++r)
                    v[r] = acc[mi][ni][r] + (bias ? bias[n0 + r] : 0.f);
                *(f32x4*)((float*)outp + (size_t)m * N + n0) = v;
            } else if (EPI == 3) {
                const f32x4 rv = *(const f32x4*)(res + (size_t)m * N + n0);
                f32x4 v;
#pragma unroll
                for (int r = 0; r < 4; ++r)
                    v[r] = rv[r] + rscale * (acc[mi][ni][r] + (bias ? bias[n0 + r] : 0.f));
                *(f32x4*)((float*)outp + (size_t)m * N + n0) = v;
            } else {                          // EPI 4: GLU pairs (interleaved cols)
                float vv[4];
#pragma unroll
                for (int r = 0; r < 4; ++r) {
                    const int n = n0 + r;
                    vv[r] = acc[mi][ni][r] + bias[((n & 1) << 10) + (n >> 1)];
                }
                union { uint32_t u; u16 hh[2]; } ok;
                ok.hh[0] = f2bf(vv[0] / (1.f + __expf(-vv[1])));
                ok.hh[1] = f2bf(vv[2] / (1.f + __expf(-vv[3])));
                *(uint32_t*)((u16*)outp + (size_t)m * (N >> 1) + (n0 >> 1)) = ok.u;
            }
        }
    }
}

// ---------- RoPE tables: ctab/stab [T=1024][32] ----------
__global__ __launch_bounds__(256) void rope_tables_kernel(float* __restrict__ ct,
                                                          float* __restrict__ st) {
    const int i = blockIdx.x * 256 + threadIdx.x;   // 32768
    const int t = i >> 5, j = i & 31;
    const float inv = powf(10000.f, -(float)j / 32.f);
    const float f = (float)t * inv;
    ct[i] = cosf(f);
    st[i] = sinf(f);
}

// ---------- RoPE apply in place on bf16, optional output scale ----------
__global__ __launch_bounds__(256) void rope_kernel(u16* __restrict__ buf,
                                                   const float* __restrict__ ct,
                                                   const float* __restrict__ st,
                                                   int hmask, int hshift, int rstride,
                                                   float scale) {
    const int i = blockIdx.x * 256 + threadIdx.x;
    const int j = i & 31;
    const int hh = (i >> 5) & hmask;
    const int m = i >> (5 + hshift);
    const int t = m & 1023;
    u16* p = buf + (size_t)m * rstride + hh * 64 + j;
    const float c = ct[t * 32 + j], s = st[t * 32 + j];
    const float x1 = bf2f(p[0]), x2 = bf2f(p[32]);
    p[0]  = f2bf((x1 * c - x2 * s) * scale);
    p[32] = f2bf((x2 * c + x1 * s) * scale);
}

// ---------- V transpose: KV[(b*1024+t)*512 + 256 + kh*64 + hd] -> Vt[(b*4+kh)*64+hd][t] ----------
__global__ __launch_bounds__(256) void vtranspose_kernel(const u16* __restrict__ KV,
                                                         u16* __restrict__ Vt) {
    __shared__ u16 tile[32][33];
    const int t0 = blockIdx.x * 32, h0 = blockIdx.y * 32;
    const int bk = blockIdx.z;                 // b*4 + kh
    const int b = bk >> 2, kh = bk & 3;
    const int tx = threadIdx.x & 31, ty = threadIdx.x >> 5;
    for (int i = 0; i < 4; ++i)
        tile[ty + i * 8][tx] =
            KV[(size_t)(b * 1024 + t0 + ty + i * 8) * 512 + 256 + kh * 64 + h0 + tx];
    __syncthreads();
    for (int i = 0; i < 4; ++i)
        Vt[((size_t)bk * 64 + h0 + ty + i * 8) * 1024 + t0 + tx] = tile[tx][ty + i * 8];
}

// ---------- fused SDPA v3: LDS-staged K/V shared by the 4 GQA heads ----------
__global__ __launch_bounds__(256) void attn_kernel(const u16* __restrict__ Q,
                                                   const u16* __restrict__ KV,
                                                   const u16* __restrict__ Vt,
                                                   u16* __restrict__ O) {
    __shared__ __align__(16) u16 sK[2][64 * 64];
    __shared__ __align__(16) u16 sV[2][64 * 64];
    __shared__ __align__(16) u16 sP[4][16 * 64];
    const int tid = threadIdx.x, lane = tid & 63, w = tid >> 6;
    const int fr = lane & 15, fq = lane >> 4, frx = fr & 7;
    const int bk = blockIdx.x, b = bk >> 2, kh = bk & 3;
    const int h = kh * 4 + w;
    const int q0 = blockIdx.y * 16;
    const int qrow = b * 1024 + q0 + fr;

    // --- per-lane staging source (pre-swizzled slot; row&7 == (lane>>3)&7) ---
    const int srow = w * 16 + (lane >> 3);                 // 8 rows per gload16
    const int sslot = (lane & 7) ^ ((lane >> 3) & 7);
    const u16* gK = KV + (size_t)(b * 1024 + srow) * 512 + kh * 64 + sslot * 8;
    const u16* gV = Vt + (size_t)((b * 4 + kh) * 64 + srow) * 1024 + sslot * 8;
    u16* dK = (u16*)sK + w * 16 * 64;                      // wave-uniform LDS bases
    u16* dV = (u16*)sV + w * 16 * 64;

    bf16x8 qf[2];
    qf[0] = *(const bf16x8*)(Q + (size_t)qrow * 1024 + h * 64 + fq * 8);
    qf[1] = *(const bf16x8*)(Q + (size_t)qrow * 1024 + h * 64 + 32 + fq * 8);

    f32x4 oacc[4] = {};
    float mrun = -1e30f, lrun = 0.f;
    u16* sPw = sP[w];

    // prologue: stage tile 0 into buf 0
    gload16(gK, dK);
    gload16(gK + (size_t)8 * 512, dK + 8 * 64);
    gload16(gV, dV);
    gload16(gV + (size_t)8 * 1024, dV + 8 * 64);
    __syncthreads();                                       // drains vmcnt + barrier

    int cur = 0;
    for (int t = 0; t < 16; ++t) {
        const int kv0 = t * 64;
        // ---- stage next tile into buf[cur^1] (overlaps with compute below) ----
        if (t < 15) {
            const int kn = kv0 + 64;
            const int nx = (cur ^ 1) * 4096;
            gload16(gK + (size_t)kn * 512,       dK + nx);
            gload16(gK + (size_t)(kn + 8) * 512, dK + nx + 8 * 64);
            gload16(gV + kn,                     dV + nx);
            gload16(gV + kn + (size_t)8 * 1024,  dV + nx + 8 * 64);
        }
        const u16* sKc = (u16*)sK + cur * 4096;
        const u16* sVc = (u16*)sV + cur * 4096;
        // ---- S^T = K x Q^T (Q pre-scaled by 1/8 in rope) ----
        f32x4 sacc[4] = {};
#pragma unroll
        for (int ks = 0; ks < 2; ++ks)
#pragma unroll
            for (int nb = 0; nb < 4; ++nb) {
                const bf16x8 kf = *(const bf16x8*)(
                    sKc + (nb * 16 + fr) * 64 + (((ks * 4 + fq) ^ frx) << 3));
                sacc[nb] = __builtin_amdgcn_mfma_f32_16x16x32_bf16(kf, qf[ks], sacc[nb], 0, 0, 0);
            }
        // ---- in-lane max over 16 kv, then reduce across the 4 fq lanes ----
        float pm;
        {
            float a0 = fmaxf(fmaxf(sacc[0][0], sacc[0][1]), fmaxf(sacc[0][2], sacc[0][3]));
            float a1 = fmaxf(fmaxf(sacc[1][0], sacc[1][1]), fmaxf(sacc[1][2], sacc[1][3]));
            float a2 = fmaxf(fmaxf(sacc[2][0], sacc[2][1]), fmaxf(sacc[2][2], sacc[2][3]));
            float a3 = fmaxf(fmaxf(sacc[3][0], sacc[3][1]), fmaxf(sacc[3][2], sacc[3][3]));
            pm = fmaxf(fmaxf(a0, a1), fmaxf(a2, a3));
        }
        pm = fmaxf(pm, __shfl_xor(pm, 16, 64));
        pm = fmaxf(pm, __shfl_xor(pm, 32, 64));
        // ---- T13: rescale only when max grew past threshold ----
        if (!__all(pm <= mrun + 8.f)) {
            const float mn = fmaxf(mrun, pm);
            const float al = __expf(mrun - mn);
            mrun = mn;
            lrun *= al;
#pragma unroll
            for (int f = 0; f < 4; ++f) {
                f32x4 tt = oacc[f];
#pragma unroll
                for (int r = 0; r < 4; ++r) tt[r] *= al;
                oacc[f] = tt;
            }
        }
        // ---- P = exp(S - m), in-lane rowsum, pack to swizzled LDS slab ----
        float rs = 0.f;
#pragma unroll
        for (int nb = 0; nb < 4; ++nb) {
            union { uint2 u2; u16 hh[4]; } pk;
#pragma unroll
            for (int r = 0; r < 4; ++r) {
                const float p = __expf(sacc[nb][r] - mrun);
                rs += p;
                pk.hh[r] = f2bf(p);
            }
            const int slotl = nb * 2 + (fq >> 1);
            *(uint2*)(sPw + fr * 64 + (((slotl ^ frx) << 3) | ((fq & 1) << 2))) = pk.u2;
        }
        rs += __shfl_xor(rs, 16, 64);
        rs += __shfl_xor(rs, 32, 64);
        lrun += rs;
        // wave-local P write->read ordering (rule #18: drain + sched fence)
        asm volatile("s_waitcnt lgkmcnt(0)" ::: "memory");
        __builtin_amdgcn_sched_barrier(0);
        // ---- O^T += V^T x P^T ----
#pragma unroll
        for (int ks2 = 0; ks2 < 2; ++ks2) {
            const bf16x8 pf = *(const bf16x8*)(
                sPw + fr * 64 + (((ks2 * 4 + fq) ^ frx) << 3));
#pragma unroll
            for (int f = 0; f < 4; ++f) {
                const bf16x8 vf = *(const bf16x8*)(
                    sVc + (f * 16 + fr) * 64 + (((ks2 * 4 + fq) ^ frx) << 3));
                oacc[f] = __builtin_amdgcn_mfma_f32_16x16x32_bf16(vf, pf, oacc[f], 0, 0, 0);
            }
        }
        __syncthreads();                                   // drains vmcnt (next tile ready)
        cur ^= 1;
    }

    const float linv = 1.f / lrun;
#pragma unroll
    for (int f = 0; f < 4; ++f) {
        union { uint2 u2; u16 hh[4]; } ok;
#pragma unroll
        for (int r = 0; r < 4; ++r) ok.hh[r] = f2bf(oacc[f][r] * linv);
        *(uint2*)(O + (size_t)qrow * 1024 + h * 64 + f * 16 + fq * 4) = ok.u2;
    }
}

// ---------- depthwise conv(K=31) + BN + SiLU: [B,T,D] bf16 -> bf16 ----------
__global__ __launch_bounds__(256) void dwconv_kernel(const u16* __restrict__ G,
                                                     const float* __restrict__ wt,
                                                     const float* __restrict__ wb,
                                                     const float* __restrict__ bg,
                                                     const float* __restrict__ bb,
                                                     const float* __restrict__ rm,
                                                     const float* __restrict__ rv,
                                                     u16* __restrict__ out) {
    __shared__ u16 sg[38 * 256];
    const int tid = threadIdx.x;
    const int d = blockIdx.x * 256 + tid;
    const int t0 = blockIdx.y * 8;
    const int b = blockIdx.z;
    const size_t base = (size_t)b * 1024 * 1024 + d;
    for (int i = 0; i < 38; ++i) {
        const int t = t0 - 15 + i;
        sg[i * 256 + tid] = (t >= 0 && t < 1024) ? G[base + (size_t)t * 1024] : (u16)0;
    }
    __syncthreads();
    float wreg[31];
#pragma unroll
    for (int k = 0; k < 31; ++k) wreg[k] = wt[d * 31 + k];
    const float scale = bg[d] * rsqrtf(rv[d] + 1e-5f);
    const float addv = wb[d] - rm[d];
#pragma unroll
    for (int j = 0; j < 8; ++j) {
        float acc = 0.f;
#pragma unroll
        for (int k = 0; k < 31; ++k) acc += bf2f(sg[(j + k) * 256 + tid]) * wreg[k];
        float y = (acc + addv) * scale + bb[d];
        y = y / (1.f + __expf(-y));               // silu
        out[base + (size_t)(t0 + j) * 1024] = f2bf(y);
    }
}

// =====================================================================
extern "C" void kernel_launch(void* const* d_in, const int* in_sizes, int n_in,
                              void* d_out, int out_size, void* d_ws, size_t ws_size,
                              hipStream_t stream) {
    (void)in_sizes; (void)n_in; (void)out_size;

    const float* x       = (const float*)d_in[0];
    const float* ff1_ng  = (const float*)d_in[1];
    const float* ff1_nb  = (const float*)d_in[2];
    const float* ff1_w1  = (const float*)d_in[3];
    const float* ff1_b1  = (const float*)d_in[4];
    const float* ff1_w2  = (const float*)d_in[5];
    const float* ff1_b2  = (const float*)d_in[6];
    const float* attn_ng = (const float*)d_in[7];
    const float* attn_nb = (const float*)d_in[8];
    const float* wq      = (const float*)d_in[9];
    const float* wkva    = (const float*)d_in[10];
    const float* kvn_g   = (const float*)d_in[11];
    const float* kvn_b   = (const float*)d_in[12];
    const float* wkvb    = (const float*)d_in[13];
    const float* wo      = (const float*)d_in[14];
    const float* conv_ng = (const float*)d_in[15];
    const float* conv_nb = (const float*)d_in[16];
    const float* pw1_w   = (const float*)d_in[17];
    const float* pw1_b   = (const float*)d_in[18];
    const float* dw_w    = (const float*)d_in[19];
    const float* dw_b    = (const float*)d_in[20];
    const float* bn_g    = (const float*)d_in[21];
    const float* bn_b    = (const float*)d_in[22];
    const float* bn_rm   = (const float*)d_in[23];
    const float* bn_rv   = (const float*)d_in[24];
    const float* pw2_w   = (const float*)d_in[25];
    const float* pw2_b   = (const float*)d_in[26];
    const float* ff2_ng  = (const float*)d_in[27];
    const float* ff2_nb  = (const float*)d_in[28];
    const float* ff2_w1  = (const float*)d_in[29];
    const float* ff2_b1  = (const float*)d_in[30];
    const float* ff2_w2  = (const float*)d_in[31];
    const float* ff2_b2  = (const float*)d_in[32];
    const float* fin_g   = (const float*)d_in[33];
    const float* fin_b   = (const float*)d_in[34];

    const int M = 8192;        // B*T
    char* ws = (char*)d_ws;
    size_t off = 0;
    auto alloc = [&](size_t bytes) {
        size_t o = off;
        off += (bytes + 255) & ~(size_t)255;
        return o;
    };
    // bf16 transposed weights [N][K]
    const size_t o_ff1w1 = alloc((size_t)4096 * 1024 * 2);
    const size_t o_ff1w2 = alloc((size_t)1024 * 4096 * 2);
    const size_t o_wq    = alloc((size_t)1024 * 1024 * 2);
    const size_t o_wkva  = alloc((size_t)256 * 1024 * 2);
    const size_t o_wkvb  = alloc((size_t)512 * 256 * 2);
    const size_t o_wo    = alloc((size_t)1024 * 1024 * 2);
    const size_t o_pw1   = alloc((size_t)2048 * 1024 * 2);
    const size_t o_pw2   = alloc((size_t)1024 * 1024 * 2);
    const size_t o_ff2w1 = alloc((size_t)4096 * 1024 * 2);
    const size_t o_ff2w2 = alloc((size_t)1024 * 4096 * 2);
    const size_t o_ctab  = alloc((size_t)1024 * 32 * 4);
    const size_t o_stab  = alloc((size_t)1024 * 32 * 4);
    const size_t o_xres  = alloc((size_t)M * 1024 * 4);     // fp32 running residual
    const size_t o_ln    = alloc((size_t)M * 1024 * 2);     // bf16 LN output
    const size_t o_bufa  = alloc((size_t)64 * 1024 * 1024); // big bf16 scratch
    if (ws_size < off) return;  // workspace too small -> clean failure signal

    // sub-offsets within BUFA
    u16* BUFA = (u16*)(ws + o_bufa);
    u16* Qb    = BUFA;                                   // 16 MB
    u16* KVb   = (u16*)((char*)BUFA + (16u << 20));      // 8 MB
    float* KVA = (float*)((char*)BUFA + (24u << 20));    // 8 MB fp32
    u16* LAT   = (u16*)((char*)BUFA + (32u << 20));      // 4 MB
    u16* VT    = (u16*)((char*)BUFA + (36u << 20));      // 4 MB
    u16* OB    = (u16*)((char*)BUFA + (40u << 20));      // 16 MB
    u16* PW1G  = BUFA;                                   // 16 MB (GLU out, conv phase)
    u16* CONVO = (u16*)((char*)BUFA + (16u << 20));      // 16 MB
    u16* HID   = BUFA;                                   // 64 MB (FFN phase)

    u16* WT_FF1W1 = (u16*)(ws + o_ff1w1);
    u16* WT_FF1W2 = (u16*)(ws + o_ff1w2);
    u16* WT_WQ    = (u16*)(ws + o_wq);
    u16* WT_WKVA  = (u16*)(ws + o_wkva);
    u16* WT_WKVB  = (u16*)(ws + o_wkvb);
    u16* WT_WO    = (u16*)(ws + o_wo);
    u16* WT_PW1   = (u16*)(ws + o_pw1);
    u16* WT_PW2   = (u16*)(ws + o_pw2);
    u16* WT_FF2W1 = (u16*)(ws + o_ff2w1);
    u16* WT_FF2W2 = (u16*)(ws + o_ff2w2);
    float* CT = (float*)(ws + o_ctab);
    float* ST = (float*)(ws + o_stab);
    float* XR = (float*)(ws + o_xres);
    u16* LNB  = (u16*)(ws + o_ln);

    // --- weight conversion (transpose to [N][K] bf16; pw1 gets GLU col-interleave) ---
    wconvert_t<0><<<dim3(32, 128), 256, 0, stream>>>(ff1_w1, WT_FF1W1, 1024, 4096, 4096);
    wconvert_t<0><<<dim3(128, 32), 256, 0, stream>>>(ff1_w2, WT_FF1W2, 4096, 1024, 1024);
    wconvert_t<0><<<dim3(32, 32),  256, 0, stream>>>(wq,     WT_WQ,    1024, 1024, 1024);
    wconvert_t<0><<<dim3(32, 8),   256, 0, stream>>>(wkva,   WT_WKVA,  1024, 256,  320);
    wconvert_t<0><<<dim3(8, 16),   256, 0, stream>>>(wkvb,   WT_WKVB,  256,  512,  512);
    wconvert_t<0><<<dim3(32, 32),  256, 0, stream>>>(wo,     WT_WO,    1024, 1024, 1024);
    wconvert_t<1><<<dim3(32, 64),  256, 0, stream>>>(pw1_w,  WT_PW1,   1024, 2048, 2048);
    wconvert_t<0><<<dim3(32, 32),  256, 0, stream>>>(pw2_w,  WT_PW2,   1024, 1024, 1024);
    wconvert_t<0><<<dim3(32, 128), 256, 0, stream>>>(ff2_w1, WT_FF2W1, 1024, 4096, 4096);
    wconvert_t<0><<<dim3(128, 32), 256, 0, stream>>>(ff2_w2, WT_FF2W2, 4096, 1024, 1024);
    rope_tables_kernel<<<128, 256, 0, stream>>>(CT, ST);

    // --- FFN1 (macaron half) ---
    ln_kernel<0><<<M, 256, 0, stream>>>(x, ff1_ng, ff1_nb, LNB, 1024);
    gemm_bf16<1><<<2048, 256, 0, stream>>>(LNB, WT_FF1W1, ff1_b1, nullptr, 0.f, HID, M, 4096, 1024, 32);
    gemm_bf16<3><<<512, 256, 0, stream>>>(HID, WT_FF1W2, ff1_b2, x, 0.5f, XR, M, 1024, 4096, 8);

    // --- attention (RMLA) ---
    ln_kernel<0><<<M, 256, 0, stream>>>(XR, attn_ng, attn_nb, LNB, 1024);
    gemm_bf16<0><<<512, 256, 0, stream>>>(LNB, WT_WQ, nullptr, nullptr, 0.f, Qb, M, 1024, 1024, 8);
    gemm_bf16<2><<<128, 256, 0, stream>>>(LNB, WT_WKVA, nullptr, nullptr, 0.f, KVA, M, 256, 1024, 2);
    ln_kernel<0><<<M, 256, 0, stream>>>(KVA, kvn_g, kvn_b, LAT, 256);
    gemm_bf16<0><<<256, 256, 0, stream>>>(LAT, WT_WKVB, nullptr, nullptr, 0.f, KVb, M, 512, 256, 4);
    rope_kernel<<<16384, 256, 0, stream>>>(Qb, CT, ST, 15, 4, 1024, 0.125f);  // fold 1/sqrt(64)
    rope_kernel<<<4096, 256, 0, stream>>>(KVb, CT, ST, 3, 2, 512, 1.0f);
    vtranspose_kernel<<<dim3(32, 2, 32), 256, 0, stream>>>(KVb, VT);
    attn_kernel<<<dim3(32, 64), 256, 0, stream>>>(Qb, KVb, VT, OB);
    gemm_bf16<3><<<512, 256, 0, stream>>>(OB, WT_WO, nullptr, XR, 1.f, XR, M, 1024, 1024, 8);

    // --- conv module (GLU fused into pw1 epilogue) ---
    ln_kernel<0><<<M, 256, 0, stream>>>(XR, conv_ng, conv_nb, LNB, 1024);
    gemm_bf16<4><<<1024, 256, 0, stream>>>(LNB, WT_PW1, pw1_b, nullptr, 0.f, PW1G, M, 2048, 1024, 16);
    dwconv_kernel<<<dim3(4, 128, 8), 256, 0, stream>>>(PW1G, dw_w, dw_b, bn_g, bn_b, bn_rm, bn_rv, CONVO);
    gemm_bf16<3><<<512, 256, 0, stream>>>(CONVO, WT_PW2, pw2_b, XR, 1.f, XR, M, 1024, 1024, 8);

    // --- FFN2 (macaron half) ---
    ln_kernel<0><<<M, 256, 0, stream>>>(XR, ff2_ng, ff2_nb, LNB, 1024);
    gemm_bf16<1><<<2048, 256, 0, stream>>>(LNB, WT_FF2W1, ff2_b1, nullptr, 0.f, HID, M, 4096, 1024, 32);
    gemm_bf16<3><<<512, 256, 0, stream>>>(HID, WT_FF2W2, ff2_b2, XR, 0.5f, XR, M, 1024, 4096, 8);

    // --- final LN -> d_out (fp32) ---
    ln_kernel<1><<<M, 256, 0, stream>>>(XR, fin_g, fin_b, d_out, 1024);
}

// Round 5
// 756.318 us; speedup vs baseline: 1.4548x; 1.0709x over previous
//
#include <hip/hip_runtime.h>
#include <stdint.h>

typedef unsigned short u16;
using bf16x8 = __attribute__((ext_vector_type(8))) __bf16;
using f32x4  = __attribute__((ext_vector_type(4))) float;

// ---------- helpers ----------
__device__ __forceinline__ u16 f2bf(float f) {
    uint32_t u = __float_as_uint(f);
    u += 0x7fffu + ((u >> 16) & 1u);          // round-to-nearest-even
    return (u16)(u >> 16);
}
__device__ __forceinline__ float bf2f(u16 u) {
    return __uint_as_float(((uint32_t)u) << 16);
}
__device__ __forceinline__ void gload16(const void* g, void* l) {
    // async global->LDS, 16B per lane; LDS dest = wave-uniform base + lane*16
    __builtin_amdgcn_global_load_lds(
        (__attribute__((address_space(1))) void*)(uintptr_t)g,
        (__attribute__((address_space(3))) void*)(uintptr_t)l,
        16, 0, 0);
}

// ---------- LayerNorm: fp32 in -> bf16 (mode 0) or fp32 (mode 1) out ----------
template <int OUTF32>
__global__ __launch_bounds__(256) void ln_kernel(const float* __restrict__ in,
                                                 const float* __restrict__ g,
                                                 const float* __restrict__ b,
                                                 void* __restrict__ out, int D) {
    const int row = blockIdx.x;
    const int tid = threadIdx.x;
    const float* x = in + (size_t)row * D;
    const int nv = D >> 8;                    // 4 for D=1024, 1 for D=256
    float v[4];
    float s1 = 0.f, s2 = 0.f;
    for (int i = 0; i < nv; ++i) {
        float t = x[tid + (i << 8)];
        v[i] = t; s1 += t; s2 += t * t;
    }
    for (int o = 1; o < 64; o <<= 1) {
        s1 += __shfl_xor(s1, o, 64);
        s2 += __shfl_xor(s2, o, 64);
    }
    __shared__ float r1[4], r2[4];
    const int w = tid >> 6;
    if ((tid & 63) == 0) { r1[w] = s1; r2[w] = s2; }
    __syncthreads();
    s1 = r1[0] + r1[1] + r1[2] + r1[3];
    s2 = r2[0] + r2[1] + r2[2] + r2[3];
    const float mean = s1 / (float)D;
    const float var  = s2 / (float)D - mean * mean;
    const float inv  = rsqrtf(var + 1e-5f);
    for (int i = 0; i < nv; ++i) {
        int c = tid + (i << 8);
        float y = (v[i] - mean) * inv * g[c] + b[c];
        if (OUTF32) ((float*)out)[(size_t)row * D + c] = y;
        else        ((u16*)out)[(size_t)row * D + c] = f2bf(y);
    }
}

// ---------- weight transpose + fp32->bf16 convert ----------
template <int GLUPERM>
__global__ __launch_bounds__(256) void wconvert_t(const float* __restrict__ W,
                                                  u16* __restrict__ Wt,
                                                  int K, int N, int ldw) {
    __shared__ float tile[32][33];
    const int k0 = blockIdx.x * 32, n0 = blockIdx.y * 32;
    const int tx = threadIdx.x & 31, ty = threadIdx.x >> 5;  // 32 x 8
    const int csrc = GLUPERM ? ((tx & 1) * 1024 + (n0 >> 1) + (tx >> 1)) : (n0 + tx);
    for (int i = 0; i < 4; ++i)
        tile[ty + i * 8][tx] = W[(size_t)(k0 + ty + i * 8) * ldw + csrc];
    __syncthreads();
    for (int i = 0; i < 4; ++i)
        Wt[(size_t)(n0 + ty + i * 8) * K + k0 + tx] = f2bf(tile[tx][ty + i * 8]);
}

// ================= GEMM 256xBN, 8 waves, counted-vmcnt pipeline =============
// C[M,N] = A[M,K] * Bt[N,K]^T. BM=256, BN=WN*64, BK=64. 512 threads.
// Per K-step: 2 phases (kslot 0/1); stage K-step s+2 into the buffer whose
// reads just drained (barrier#1); vmcnt(LOADS) waits only for s+1's loads
// (s+2's stay in flight across barrier#2) -- never drains to 0 in steady state.
// EPI: 0 = bf16 out ; 1 = silu bf16 (+bias) ; 3 = f32 res + rscale*(acc+bias) ;
//      4 = GLU pairs -> bf16 [M][N/2]
template <int EPI, int WM>
__global__ __launch_bounds__(512, 2) void gemm256(const u16* __restrict__ A,
                                                  const u16* __restrict__ Bt,
                                                  const float* __restrict__ bias,
                                                  const float* __restrict__ res,
                                                  float rscale,
                                                  void* __restrict__ outp,
                                                  int M, int N, int K, int nbx) {
    constexpr int WN = 8 / WM;
    constexpr int BN = WN * 64;
    constexpr int FM = 16 / WM;               // A frags per wave (m)
    __shared__ u16 sA[2][256 * 64];
    __shared__ u16 sB[2][BN * 64];
    const int tid = threadIdx.x, lane = tid & 63, w = tid >> 6;
    const int wm = w / WN, wn = w % WN;
    const int fr = lane & 15, fq = lane >> 4, frx = fr & 7;
    // XCD-aware bijective swizzle (gridDim.x % 8 == 0 at all call sites)
    const int cpx = gridDim.x >> 3;
    const int lid = (blockIdx.x & 7) * cpx + (blockIdx.x >> 3);
    const int bn0 = (lid % nbx) * BN;
    const int bm0 = (lid / nbx) * 256;

    f32x4 acc[FM][4] = {};

    // staging: one gload16 call = each wave writes 8 rows (1KB) at its base
    const int lrow = lane >> 3;
    const int lslot = (lane & 7) ^ (lrow & 7);            // pre-swizzled source
    const u16* ga = A  + (size_t)(bm0 + w * 8 + lrow) * K + lslot * 8;
    const u16* gb = Bt + (size_t)(bn0 + w * 8 + lrow) * K + lslot * 8;
    const size_t rs64 = (size_t)64 * K;
    const int lbase = w * 8 * 64;                          // wave-uniform elems

    const int NK = K >> 6;

#define STAGE(bufi, kt)                                                        \
    {                                                                          \
        _Pragma("unroll")                                                      \
        for (int i = 0; i < 4; ++i)                                            \
            gload16(ga + (kt) + i * rs64, &sA[bufi][lbase + i * 4096]);        \
        _Pragma("unroll")                                                      \
        for (int i = 0; i < BN / 64; ++i)                                      \
            gload16(gb + (kt) + i * rs64, &sB[bufi][lbase + i * 4096]);        \
    }

    // prologue: K-steps 0 and 1 in flight; wait for K0 only
    STAGE(0, 0)
    STAGE(1, 64)
    if constexpr (WM == 2) asm volatile("s_waitcnt vmcnt(8)" ::: "memory");
    else                   asm volatile("s_waitcnt vmcnt(6)" ::: "memory");
    __builtin_amdgcn_sched_barrier(0);
    __builtin_amdgcn_s_barrier();

    const int arow0 = wm * (256 / WM) + fr;
    const int brow0 = wn * 64 + fr;

    for (int s = 0; s < NK; ++s) {
        const int buf = s & 1;
        bf16x8 afr[FM], bfr[4];
        // ---- phase 1: kslot 0 ----
#pragma unroll
        for (int mi = 0; mi < FM; ++mi)
            afr[mi] = *(const bf16x8*)(&sA[buf][(arow0 + mi * 16) * 64 + ((fq ^ frx) << 3)]);
#pragma unroll
        for (int ni = 0; ni < 4; ++ni)
            bfr[ni] = *(const bf16x8*)(&sB[buf][(brow0 + ni * 16) * 64 + ((fq ^ frx) << 3)]);
        asm volatile("s_waitcnt lgkmcnt(0)" ::: "memory");
        __builtin_amdgcn_sched_barrier(0);
        __builtin_amdgcn_s_setprio(1);
#pragma unroll
        for (int mi = 0; mi < FM; ++mi)
#pragma unroll
            for (int ni = 0; ni < 4; ++ni)
                acc[mi][ni] = __builtin_amdgcn_mfma_f32_16x16x32_bf16(
                    bfr[ni], afr[mi], acc[mi][ni], 0, 0, 0);   // D[n][m]
        __builtin_amdgcn_s_setprio(0);
        // ---- phase 2: kslot 1 ----
#pragma unroll
        for (int mi = 0; mi < FM; ++mi)
            afr[mi] = *(const bf16x8*)(&sA[buf][(arow0 + mi * 16) * 64 + (((4 + fq) ^ frx) << 3)]);
#pragma unroll
        for (int ni = 0; ni < 4; ++ni)
            bfr[ni] = *(const bf16x8*)(&sB[buf][(brow0 + ni * 16) * 64 + (((4 + fq) ^ frx) << 3)]);
        asm volatile("s_waitcnt lgkmcnt(0)" ::: "memory");
        __builtin_amdgcn_sched_barrier(0);
        __builtin_amdgcn_s_barrier();          // all waves done reading buf
        if (s + 2 < NK) {
            STAGE(buf, (s + 2) << 6)           // overwrite drained buf
        }
        __builtin_amdgcn_sched_barrier(0);
        __builtin_amdgcn_s_setprio(1);
#pragma unroll
        for (int mi = 0; mi < FM; ++mi)
#pragma unroll
            for (int ni = 0; ni < 4; ++ni)
                acc[mi][ni] = __builtin_amdgcn_mfma_f32_16x16x32_bf16(
                    bfr[ni], afr[mi], acc[mi][ni], 0, 0, 0);
        __builtin_amdgcn_s_setprio(0);
        // wait for K-step s+1's loads (s+2's remain in flight)
        if (s + 2 < NK) {
            if constexpr (WM == 2) asm volatile("s_waitcnt vmcnt(8)" ::: "memory");
            else                   asm volatile("s_waitcnt vmcnt(6)" ::: "memory");
        } else {
            asm volatile("s_waitcnt vmcnt(0)" ::: "memory");
        }
        __builtin_amdgcn_sched_barrier(0);
        __builtin_amdgcn_s_barrier();          // next buf ready for phase-1 reads
    }

    // epilogue: lane holds rows m = bm0+wm*(256/WM)+mi*16+fr, cols n0..n0+3
#pragma unroll
    for (int mi = 0; mi < FM; ++mi) {
        const int m = bm0 + wm * (256 / WM) + mi * 16 + fr;
#pragma unroll
        for (int ni = 0; ni < 4; ++ni) {
            const int n0 = bn0 + wn * 64 + ni * 16 + fq * 4;
            if (EPI == 0 || EPI == 1) {
                union { uint2 u2; u16 hh[4]; } ok;
#pragma unroll
                for (int r = 0; r < 4; ++r) {
                    float v = acc[mi][ni][r] + (bias ? bias[n0 + r] : 0.f);
                    if (EPI == 1) v = v / (1.f + __expf(-v));
                    ok.hh[r] = f2bf(v);
                }
                *(uint2*)((u16*)outp + (size_t)m * N + n0) = ok.u2;
            } else if (EPI == 3) {
                const f32x4 rv = *(const f32x4*)(res + (size_t)m * N + n0);
                f32x4 v;
#pragma unroll
                for (int r = 0; r < 4; ++r)
                    v[r] = rv[r] + rscale * (acc[mi][ni][r] + (bias ? bias[n0 + r] : 0.f));
                *(f32x4*)((float*)outp + (size_t)m * N + n0) = v;
            } else {                           // EPI 4: GLU pairs (interleaved cols)
                float vv[4];
#pragma unroll
                for (int r = 0; r < 4; ++r) {
                    const int n = n0 + r;
                    vv[r] = acc[mi][ni][r] + bias[((n & 1) << 10) + (n >> 1)];
                }
                union { uint32_t u; u16 hh[2]; } ok;
                ok.hh[0] = f2bf(vv[0] / (1.f + __expf(-vv[1])));
                ok.hh[1] = f2bf(vv[2] / (1.f + __expf(-vv[3])));
                *(uint32_t*)((u16*)outp + (size_t)m * (N >> 1) + (n0 >> 1)) = ok.u;
            }
        }
    }
#undef STAGE
}

// ---------- GEMM v2 (128x128, kept for small/odd shapes) ----------
// EPI: 0 = bf16 out (+bias) ; 2 = f32 out (+bias)
template <int EPI>
__global__ __launch_bounds__(256) void gemm_bf16(const u16* __restrict__ A,
                                                 const u16* __restrict__ Bt,
                                                 const float* __restrict__ bias,
                                                 const float* __restrict__ res,
                                                 float rscale,
                                                 void* __restrict__ outp,
                                                 int M, int N, int K, int nbx) {
    __shared__ u16 sA[128 * 64];
    __shared__ u16 sB[128 * 64];
    const int tid = threadIdx.x;
    const int lane = tid & 63;
    const int w = tid >> 6;
    const int wm = w >> 1, wn = w & 1;        // 2x2 wave grid
    const int fr = lane & 15, fq = lane >> 4, frx = fr & 7;
    const int cpx = gridDim.x >> 3;
    const int lid = (blockIdx.x & 7) * cpx + (blockIdx.x >> 3);
    const int bn0 = (lid % nbx) * 128;
    const int bm0 = (lid / nbx) * 128;

    f32x4 acc[4][4] = {};

    const int lrow = lane >> 3;
    const int lslot = (lane & 7) ^ lrow;
    const u16* ga0 = A  + (size_t)(bm0 + w * 8 + lrow) * K + lslot * 8;
    const u16* gb0 = Bt + (size_t)(bn0 + w * 8 + lrow) * K + lslot * 8;
    u16* la0 = sA + w * 512;
    u16* lb0 = sB + w * 512;
    const size_t rstep32 = (size_t)32 * K;

    for (int kt = 0; kt < K; kt += 64) {
        __syncthreads();
#pragma unroll
        for (int i = 0; i < 4; ++i) {
            gload16(ga0 + kt + i * rstep32, la0 + i * 2048);
            gload16(gb0 + kt + i * rstep32, lb0 + i * 2048);
        }
        __syncthreads();
#pragma unroll
        for (int kk = 0; kk < 2; ++kk) {
            bf16x8 afr[4], bfr[4];
            const int sl = (((kk * 4 + fq) ^ frx) << 3);
#pragma unroll
            for (int i = 0; i < 4; ++i) {
                afr[i] = *(const bf16x8*)(sA + (wm * 64 + i * 16 + fr) * 64 + sl);
                bfr[i] = *(const bf16x8*)(sB + (wn * 64 + i * 16 + fr) * 64 + sl);
            }
#pragma unroll
            for (int mi = 0; mi < 4; ++mi)
#pragma unroll
                for (int ni = 0; ni < 4; ++ni)
                    acc[mi][ni] = __builtin_amdgcn_mfma_f32_16x16x32_bf16(
                        bfr[ni], afr[mi], acc[mi][ni], 0, 0, 0);
        }
    }

#pragma unroll
    for (int mi = 0; mi < 4; ++mi) {
        const int m = bm0 + wm * 64 + mi * 16 + fr;
#pragma unroll
        for (int ni = 0; ni < 4; ++ni) {
            const int n0 = bn0 + wn * 64 + ni * 16 + fq * 4;
            if (EPI == 0) {
                union { uint2 u2; u16 hh[4]; } ok;
#pragma unroll
                for (int r = 0; r < 4; ++r)
                    ok.hh[r] = f2bf(acc[mi][ni][r] + (bias ? bias[n0 + r] : 0.f));
                *(uint2*)((u16*)outp + (size_t)m * N + n0) = ok.u2;
            } else {
                f32x4 v;
#pragma unroll
                for (int r = 0; r < 4; ++r)
                    v[r] = acc[mi][ni][r] + (bias ? bias[n0 + r] : 0.f);
                *(f32x4*)((float*)outp + (size_t)m * N + n0) = v;
            }
        }
    }
}

// ---------- RoPE tables ----------
__global__ __launch_bounds__(256) void rope_tables_kernel(float* __restrict__ ct,
                                                          float* __restrict__ st) {
    const int i = blockIdx.x * 256 + threadIdx.x;   // 32768
    const int t = i >> 5, j = i & 31;
    const float inv = powf(10000.f, -(float)j / 32.f);
    const float f = (float)t * inv;
    ct[i] = cosf(f);
    st[i] = sinf(f);
}

// ---------- RoPE apply ----------
__global__ __launch_bounds__(256) void rope_kernel(u16* __restrict__ buf,
                                                   const float* __restrict__ ct,
                                                   const float* __restrict__ st,
                                                   int hmask, int hshift, int rstride,
                                                   float scale) {
    const int i = blockIdx.x * 256 + threadIdx.x;
    const int j = i & 31;
    const int hh = (i >> 5) & hmask;
    const int m = i >> (5 + hshift);
    const int t = m & 1023;
    u16* p = buf + (size_t)m * rstride + hh * 64 + j;
    const float c = ct[t * 32 + j], s = st[t * 32 + j];
    const float x1 = bf2f(p[0]), x2 = bf2f(p[32]);
    p[0]  = f2bf((x1 * c - x2 * s) * scale);
    p[32] = f2bf((x2 * c + x1 * s) * scale);
}

// ---------- V transpose ----------
__global__ __launch_bounds__(256) void vtranspose_kernel(const u16* __restrict__ KV,
                                                         u16* __restrict__ Vt) {
    __shared__ u16 tile[32][33];
    const int t0 = blockIdx.x * 32, h0 = blockIdx.y * 32;
    const int bk = blockIdx.z;                 // b*4 + kh
    const int b = bk >> 2, kh = bk & 3;
    const int tx = threadIdx.x & 31, ty = threadIdx.x >> 5;
    for (int i = 0; i < 4; ++i)
        tile[ty + i * 8][tx] =
            KV[(size_t)(b * 1024 + t0 + ty + i * 8) * 512 + 256 + kh * 64 + h0 + tx];
    __syncthreads();
    for (int i = 0; i < 4; ++i)
        Vt[((size_t)bk * 64 + h0 + ty + i * 8) * 1024 + t0 + tx] = tile[tx][ty + i * 8];
}

// ---------- fused SDPA v3: LDS-staged K/V shared by the 4 GQA heads ----------
__global__ __launch_bounds__(256) void attn_kernel(const u16* __restrict__ Q,
                                                   const u16* __restrict__ KV,
                                                   const u16* __restrict__ Vt,
                                                   u16* __restrict__ O) {
    __shared__ __align__(16) u16 sK[2][64 * 64];
    __shared__ __align__(16) u16 sV[2][64 * 64];
    __shared__ __align__(16) u16 sP[4][16 * 64];
    const int tid = threadIdx.x, lane = tid & 63, w = tid >> 6;
    const int fr = lane & 15, fq = lane >> 4, frx = fr & 7;
    const int bk = blockIdx.x, b = bk >> 2, kh = bk & 3;
    const int h = kh * 4 + w;
    const int q0 = blockIdx.y * 16;
    const int qrow = b * 1024 + q0 + fr;

    const int srow = w * 16 + (lane >> 3);
    const int sslot = (lane & 7) ^ ((lane >> 3) & 7);
    const u16* gK = KV + (size_t)(b * 1024 + srow) * 512 + kh * 64 + sslot * 8;
    const u16* gV = Vt + (size_t)((b * 4 + kh) * 64 + srow) * 1024 + sslot * 8;
    u16* dK = (u16*)sK + w * 16 * 64;
    u16* dV = (u16*)sV + w * 16 * 64;

    bf16x8 qf[2];
    qf[0] = *(const bf16x8*)(Q + (size_t)qrow * 1024 + h * 64 + fq * 8);
    qf[1] = *(const bf16x8*)(Q + (size_t)qrow * 1024 + h * 64 + 32 + fq * 8);

    f32x4 oacc[4] = {};
    float mrun = -1e30f, lrun = 0.f;
    u16* sPw = sP[w];

    gload16(gK, dK);
    gload16(gK + (size_t)8 * 512, dK + 8 * 64);
    gload16(gV, dV);
    gload16(gV + (size_t)8 * 1024, dV + 8 * 64);
    __syncthreads();

    int cur = 0;
    for (int t = 0; t < 16; ++t) {
        const int kv0 = t * 64;
        if (t < 15) {
            const int kn = kv0 + 64;
            const int nx = (cur ^ 1) * 4096;
            gload16(gK + (size_t)kn * 512,       dK + nx);
            gload16(gK + (size_t)(kn + 8) * 512, dK + nx + 8 * 64);
            gload16(gV + kn,                     dV + nx);
            gload16(gV + kn + (size_t)8 * 1024,  dV + nx + 8 * 64);
        }
        const u16* sKc = (u16*)sK + cur * 4096;
        const u16* sVc = (u16*)sV + cur * 4096;
        f32x4 sacc[4] = {};
#pragma unroll
        for (int ks = 0; ks < 2; ++ks)
#pragma unroll
            for (int nb = 0; nb < 4; ++nb) {
                const bf16x8 kf = *(const bf16x8*)(
                    sKc + (nb * 16 + fr) * 64 + (((ks * 4 + fq) ^ frx) << 3));
                sacc[nb] = __builtin_amdgcn_mfma_f32_16x16x32_bf16(kf, qf[ks], sacc[nb], 0, 0, 0);
            }
        float pm;
        {
            float a0 = fmaxf(fmaxf(sacc[0][0], sacc[0][1]), fmaxf(sacc[0][2], sacc[0][3]));
            float a1 = fmaxf(fmaxf(sacc[1][0], sacc[1][1]), fmaxf(sacc[1][2], sacc[1][3]));
            float a2 = fmaxf(fmaxf(sacc[2][0], sacc[2][1]), fmaxf(sacc[2][2], sacc[2][3]));
            float a3 = fmaxf(fmaxf(sacc[3][0], sacc[3][1]), fmaxf(sacc[3][2], sacc[3][3]));
            pm = fmaxf(fmaxf(a0, a1), fmaxf(a2, a3));
        }
        pm = fmaxf(pm, __shfl_xor(pm, 16, 64));
        pm = fmaxf(pm, __shfl_xor(pm, 32, 64));
        if (!__all(pm <= mrun + 8.f)) {
            const float mn = fmaxf(mrun, pm);
            const float al = __expf(mrun - mn);
            mrun = mn;
            lrun *= al;
#pragma unroll
            for (int f = 0; f < 4; ++f) {
                f32x4 tt = oacc[f];
#pragma unroll
                for (int r = 0; r < 4; ++r) tt[r] *= al;
                oacc[f] = tt;
            }
        }
        float rs = 0.f;
#pragma unroll
        for (int nb = 0; nb < 4; ++nb) {
            union { uint2 u2; u16 hh[4]; } pk;
#pragma unroll
            for (int r = 0; r < 4; ++r) {
                const float p = __expf(sacc[nb][r] - mrun);
                rs += p;
                pk.hh[r] = f2bf(p);
            }
            const int slotl = nb * 2 + (fq >> 1);
            *(uint2*)(sPw + fr * 64 + (((slotl ^ frx) << 3) | ((fq & 1) << 2))) = pk.u2;
        }
        rs += __shfl_xor(rs, 16, 64);
        rs += __shfl_xor(rs, 32, 64);
        lrun += rs;
        asm volatile("s_waitcnt lgkmcnt(0)" ::: "memory");
        __builtin_amdgcn_sched_barrier(0);
#pragma unroll
        for (int ks2 = 0; ks2 < 2; ++ks2) {
            const bf16x8 pf = *(const bf16x8*)(
                sPw + fr * 64 + (((ks2 * 4 + fq) ^ frx) << 3));
#pragma unroll
            for (int f = 0; f < 4; ++f) {
                const bf16x8 vf = *(const bf16x8*)(
                    sVc + (f * 16 + fr) * 64 + (((ks2 * 4 + fq) ^ frx) << 3));
                oacc[f] = __builtin_amdgcn_mfma_f32_16x16x32_bf16(vf, pf, oacc[f], 0, 0, 0);
            }
        }
        __syncthreads();
        cur ^= 1;
    }

    const float linv = 1.f / lrun;
#pragma unroll
    for (int f = 0; f < 4; ++f) {
        union { uint2 u2; u16 hh[4]; } ok;
#pragma unroll
        for (int r = 0; r < 4; ++r) ok.hh[r] = f2bf(oacc[f][r] * linv);
        *(uint2*)(O + (size_t)qrow * 1024 + h * 64 + f * 16 + fq * 4) = ok.u2;
    }
}

// ---------- depthwise conv(K=31) + BN + SiLU ----------
__global__ __launch_bounds__(256) void dwconv_kernel(const u16* __restrict__ G,
                                                     const float* __restrict__ wt,
                                                     const float* __restrict__ wb,
                                                     const float* __restrict__ bg,
                                                     const float* __restrict__ bb,
                                                     const float* __restrict__ rm,
                                                     const float* __restrict__ rv,
                                                     u16* __restrict__ out) {
    __shared__ u16 sg[38 * 256];
    const int tid = threadIdx.x;
    const int d = blockIdx.x * 256 + tid;
    const int t0 = blockIdx.y * 8;
    const int b = blockIdx.z;
    const size_t base = (size_t)b * 1024 * 1024 + d;
    for (int i = 0; i < 38; ++i) {
        const int t = t0 - 15 + i;
        sg[i * 256 + tid] = (t >= 0 && t < 1024) ? G[base + (size_t)t * 1024] : (u16)0;
    }
    __syncthreads();
    float wreg[31];
#pragma unroll
    for (int k = 0; k < 31; ++k) wreg[k] = wt[d * 31 + k];
    const float scale = bg[d] * rsqrtf(rv[d] + 1e-5f);
    const float addv = wb[d] - rm[d];
#pragma unroll
    for (int j = 0; j < 8; ++j) {
        float acc = 0.f;
#pragma unroll
        for (int k = 0; k < 31; ++k) acc += bf2f(sg[(j + k) * 256 + tid]) * wreg[k];
        float y = (acc + addv) * scale + bb[d];
        y = y / (1.f + __expf(-y));               // silu
        out[base + (size_t)(t0 + j) * 1024] = f2bf(y);
    }
}

// =====================================================================
extern "C" void kernel_launch(void* const* d_in, const int* in_sizes, int n_in,
                              void* d_out, int out_size, void* d_ws, size_t ws_size,
                              hipStream_t stream) {
    (void)in_sizes; (void)n_in; (void)out_size;

    const float* x       = (const float*)d_in[0];
    const float* ff1_ng  = (const float*)d_in[1];
    const float* ff1_nb  = (const float*)d_in[2];
    const float* ff1_w1  = (const float*)d_in[3];
    const float* ff1_b1  = (const float*)d_in[4];
    const float* ff1_w2  = (const float*)d_in[5];
    const float* ff1_b2  = (const float*)d_in[6];
    const float* attn_ng = (const float*)d_in[7];
    const float* attn_nb = (const float*)d_in[8];
    const float* wq      = (const float*)d_in[9];
    const float* wkva    = (const float*)d_in[10];
    const float* kvn_g   = (const float*)d_in[11];
    const float* kvn_b   = (const float*)d_in[12];
    const float* wkvb    = (const float*)d_in[13];
    const float* wo      = (const float*)d_in[14];
    const float* conv_ng = (const float*)d_in[15];
    const float* conv_nb = (const float*)d_in[16];
    const float* pw1_w   = (const float*)d_in[17];
    const float* pw1_b   = (const float*)d_in[18];
    const float* dw_w    = (const float*)d_in[19];
    const float* dw_b    = (const float*)d_in[20];
    const float* bn_g    = (const float*)d_in[21];
    const float* bn_b    = (const float*)d_in[22];
    const float* bn_rm   = (const float*)d_in[23];
    const float* bn_rv   = (const float*)d_in[24];
    const float* pw2_w   = (const float*)d_in[25];
    const float* pw2_b   = (const float*)d_in[26];
    const float* ff2_ng  = (const float*)d_in[27];
    const float* ff2_nb  = (const float*)d_in[28];
    const float* ff2_w1  = (const float*)d_in[29];
    const float* ff2_b1  = (const float*)d_in[30];
    const float* ff2_w2  = (const float*)d_in[31];
    const float* ff2_b2  = (const float*)d_in[32];
    const float* fin_g   = (const float*)d_in[33];
    const float* fin_b   = (const float*)d_in[34];

    const int M = 8192;        // B*T
    char* ws = (char*)d_ws;
    size_t off = 0;
    auto alloc = [&](size_t bytes) {
        size_t o = off;
        off += (bytes + 255) & ~(size_t)255;
        return o;
    };
    const size_t o_ff1w1 = alloc((size_t)4096 * 1024 * 2);
    const size_t o_ff1w2 = alloc((size_t)1024 * 4096 * 2);
    const size_t o_wq    = alloc((size_t)1024 * 1024 * 2);
    const size_t o_wkva  = alloc((size_t)256 * 1024 * 2);
    const size_t o_wkvb  = alloc((size_t)512 * 256 * 2);
    const size_t o_wo    = alloc((size_t)1024 * 1024 * 2);
    const size_t o_pw1   = alloc((size_t)2048 * 1024 * 2);
    const size_t o_pw2   = alloc((size_t)1024 * 1024 * 2);
    const size_t o_ff2w1 = alloc((size_t)4096 * 1024 * 2);
    const size_t o_ff2w2 = alloc((size_t)1024 * 4096 * 2);
    const size_t o_ctab  = alloc((size_t)1024 * 32 * 4);
    const size_t o_stab  = alloc((size_t)1024 * 32 * 4);
    const size_t o_xres  = alloc((size_t)M * 1024 * 4);
    const size_t o_ln    = alloc((size_t)M * 1024 * 2);
    const size_t o_bufa  = alloc((size_t)64 * 1024 * 1024);
    if (ws_size < off) return;

    u16* BUFA = (u16*)(ws + o_bufa);
    u16* Qb    = BUFA;                                   // 16 MB
    u16* KVb   = (u16*)((char*)BUFA + (16u << 20));      // 8 MB
    float* KVA = (float*)((char*)BUFA + (24u << 20));    // 8 MB fp32
    u16* LAT   = (u16*)((char*)BUFA + (32u << 20));      // 4 MB
    u16* VT    = (u16*)((char*)BUFA + (36u << 20));      // 4 MB
    u16* OB    = (u16*)((char*)BUFA + (40u << 20));      // 16 MB
    u16* PW1G  = BUFA;                                   // 16 MB (GLU out)
    u16* CONVO = (u16*)((char*)BUFA + (16u << 20));      // 16 MB
    u16* HID   = BUFA;                                   // 64 MB (FFN phase)

    u16* WT_FF1W1 = (u16*)(ws + o_ff1w1);
    u16* WT_FF1W2 = (u16*)(ws + o_ff1w2);
    u16* WT_WQ    = (u16*)(ws + o_wq);
    u16* WT_WKVA  = (u16*)(ws + o_wkva);
    u16* WT_WKVB  = (u16*)(ws + o_wkvb);
    u16* WT_WO    = (u16*)(ws + o_wo);
    u16* WT_PW1   = (u16*)(ws + o_pw1);
    u16* WT_PW2   = (u16*)(ws + o_pw2);
    u16* WT_FF2W1 = (u16*)(ws + o_ff2w1);
    u16* WT_FF2W2 = (u16*)(ws + o_ff2w2);
    float* CT = (float*)(ws + o_ctab);
    float* ST = (float*)(ws + o_stab);
    float* XR = (float*)(ws + o_xres);
    u16* LNB  = (u16*)(ws + o_ln);

    // --- weight conversion ---
    wconvert_t<0><<<dim3(32, 128), 256, 0, stream>>>(ff1_w1, WT_FF1W1, 1024, 4096, 4096);
    wconvert_t<0><<<dim3(128, 32), 256, 0, stream>>>(ff1_w2, WT_FF1W2, 4096, 1024, 1024);
    wconvert_t<0><<<dim3(32, 32),  256, 0, stream>>>(wq,     WT_WQ,    1024, 1024, 1024);
    wconvert_t<0><<<dim3(32, 8),   256, 0, stream>>>(wkva,   WT_WKVA,  1024, 256,  320);
    wconvert_t<0><<<dim3(8, 16),   256, 0, stream>>>(wkvb,   WT_WKVB,  256,  512,  512);
    wconvert_t<0><<<dim3(32, 32),  256, 0, stream>>>(wo,     WT_WO,    1024, 1024, 1024);
    wconvert_t<1><<<dim3(32, 64),  256, 0, stream>>>(pw1_w,  WT_PW1,   1024, 2048, 2048);
    wconvert_t<0><<<dim3(32, 32),  256, 0, stream>>>(pw2_w,  WT_PW2,   1024, 1024, 1024);
    wconvert_t<0><<<dim3(32, 128), 256, 0, stream>>>(ff2_w1, WT_FF2W1, 1024, 4096, 4096);
    wconvert_t<0><<<dim3(128, 32), 256, 0, stream>>>(ff2_w2, WT_FF2W2, 4096, 1024, 1024);
    rope_tables_kernel<<<128, 256, 0, stream>>>(CT, ST);

    // --- FFN1 (macaron half) ---
    ln_kernel<0><<<M, 256, 0, stream>>>(x, ff1_ng, ff1_nb, LNB, 1024);
    gemm256<1, 2><<<512, 512, 0, stream>>>(LNB, WT_FF1W1, ff1_b1, nullptr, 0.f, HID, M, 4096, 1024, 16);
    gemm256<3, 4><<<256, 512, 0, stream>>>(HID, WT_FF1W2, ff1_b2, x, 0.5f, XR, M, 1024, 4096, 8);

    // --- attention (RMLA) ---
    ln_kernel<0><<<M, 256, 0, stream>>>(XR, attn_ng, attn_nb, LNB, 1024);
    gemm256<0, 4><<<256, 512, 0, stream>>>(LNB, WT_WQ, nullptr, nullptr, 0.f, Qb, M, 1024, 1024, 8);
    gemm_bf16<2><<<128, 256, 0, stream>>>(LNB, WT_WKVA, nullptr, nullptr, 0.f, KVA, M, 256, 1024, 2);
    ln_kernel<0><<<M, 256, 0, stream>>>(KVA, kvn_g, kvn_b, LAT, 256);
    gemm_bf16<0><<<256, 256, 0, stream>>>(LAT, WT_WKVB, nullptr, nullptr, 0.f, KVb, M, 512, 256, 4);
    rope_kernel<<<16384, 256, 0, stream>>>(Qb, CT, ST, 15, 4, 1024, 0.125f);
    rope_kernel<<<4096, 256, 0, stream>>>(KVb, CT, ST, 3, 2, 512, 1.0f);
    vtranspose_kernel<<<dim3(32, 2, 32), 256, 0, stream>>>(KVb, VT);
    attn_kernel<<<dim3(32, 64), 256, 0, stream>>>(Qb, KVb, VT, OB);
    gemm256<3, 4><<<256, 512, 0, stream>>>(OB, WT_WO, nullptr, XR, 1.f, XR, M, 1024, 1024, 8);

    // --- conv module (GLU fused into pw1 epilogue) ---
    ln_kernel<0><<<M, 256, 0, stream>>>(XR, conv_ng, conv_nb, LNB, 1024);
    gemm256<4, 2><<<256, 512, 0, stream>>>(LNB, WT_PW1, pw1_b, nullptr, 0.f, PW1G, M, 2048, 1024, 8);
    dwconv_kernel<<<dim3(4, 128, 8), 256, 0, stream>>>(PW1G, dw_w, dw_b, bn_g, bn_b, bn_rm, bn_rv, CONVO);
    gemm256<3, 4><<<256, 512, 0, stream>>>(CONVO, WT_PW2, pw2_b, XR, 1.f, XR, M, 1024, 1024, 8);

    // --- FFN2 (macaron half) ---
    ln_kernel<0><<<M, 256, 0, stream>>>(XR, ff2_ng, ff2_nb, LNB, 1024);
    gemm256<1, 2><<<512, 512, 0, stream>>>(LNB, WT_FF2W1, ff2_b1, nullptr, 0.f, HID, M, 4096, 1024, 16);
    gemm256<3, 4><<<256, 512, 0, stream>>>(HID, WT_FF2W2, ff2_b2, XR, 0.5f, XR, M, 1024, 4096, 8);

    // --- final LN -> d_out (fp32) ---
    ln_kernel<1><<<M, 256, 0, stream>>>(XR, fin_g, fin_b, d_out, 1024);
}